// Round 7
// baseline (501.829 us; speedup 1.0000x reference)
//
#include <hip/hip_runtime.h>
#include <hip/hip_bf16.h>
#include <math.h>

#define BATCH 256
#define LAT 100
#define NCLS 10
#define CIN0 110
#define C1 512
#define C2 256
#define C3 128
#define NCH 3
#define EPS 1e-5f
#define NCOPY 8

typedef __hip_bfloat16 bf16;
typedef short bf16x8 __attribute__((ext_vector_type(8)));
typedef float f32x4 __attribute__((ext_vector_type(4)));

__device__ __forceinline__ float b2f(bf16 v) { return __bfloat162float(v); }
__device__ __forceinline__ bf16 f2b(float v) { return __float2bfloat16(v); }
__device__ __forceinline__ float s2f(short s) {
    unsigned u = ((unsigned)(unsigned short)s) << 16;
    return __builtin_bit_cast(float, u);
}
__device__ __forceinline__ short f2s(float f) {
    bf16 b = __float2bfloat16(f);
    return *(short*)&b;
}

__device__ __forceinline__ void gl_lds16(const void* g, void* l) {
    __builtin_amdgcn_global_load_lds(
        (__attribute__((address_space(1))) const void*)g,
        (__attribute__((address_space(3))) void*)l, 16, 0, 0);
}

// ======== INTERLEAVED complex channel layout everywhere ========
#define NB_W1 14336
#define NB_W2 32768
#define NB_W3 8192
#define NB_W4 256
#define NB_X0 224
#define NB_Z  141    // zero stat copies (35840 f) + 1KB zero-page for gload_lds OOB taps

__device__ __forceinline__ void w1prep_body(const float* wr, const float* wi, bf16* B, int idx) {
    if (idx >= 16384 * 224) return;
    int n = idx / 224, k = idx - n * 224;
    int p = n >> 10;
    int c = (n & 1023) >> 1;
    int part = n & 1;
    int pk = k >= 112; int ci = k - pk * 112;
    float v = 0.f;
    if (ci < CIN0) {
        size_t widx = ((size_t)ci * C1 + c) * 16 + p;
        float vr = wr[widx], vi = wi[widx];
        v = (part == 0) ? (pk ? -vi : vr) : (pk ? vr : vi);
    }
    B[idx] = f2b(v);
}

template<int CIN, int N>
__device__ __forceinline__ void wprep_panel_body(const float* wr, const float* wi, bf16* W,
                                                 size_t idx) {
    constexpr int TWOK = 8 * CIN, C2I = 2 * CIN;
    size_t per_cls = (size_t)2 * N * TWOK;
    if (idx >= 4 * per_cls) return;
    int cls = (int)(idx / per_cls);
    size_t r = idx - (size_t)cls * per_cls;
    size_t chunk_nb = (size_t)TWOK * 128;
    int nb = (int)(r / chunk_nb);
    int r2 = (int)(r - (size_t)nb * chunk_nb);
    int kb = r2 >> 12;
    int w = r2 & 4095;
    int f = w >> 9;
    int l = (w >> 3) & 63;
    int j = w & 7;
    int n_virt = nb * 128 + (f >> 2) * 64 + (f & 3) * 16 + (l & 15);
    int k = kb * 32 + (l >> 4) * 8 + j;
    int c = n_virt >> 1, part = n_virt & 1;
    int t = k / C2I;
    int q = k & (C2I - 1);
    int ci = q >> 1, p = q & 1;
    int py = cls >> 1, px = cls & 1;
    int a = t >> 1, e = t & 1;
    int kh = py ? (a ? 2 : 0) : (a ? 3 : 1);
    int kw = px ? (e ? 2 : 0) : (e ? 3 : 1);
    size_t widx = ((size_t)ci * N + c) * 16 + kh * 4 + kw;
    float vr = wr[widx], vi = wi[widx];
    float v = (part == 0) ? (p ? -vi : vr) : (p ? vr : vi);
    W[idx] = f2b(v);
}

// W3S: pre-swizzled staging layout for gemm3_8ph's B tiles. Linear-source staging:
// W3S[cls][kt][kh][p][tid][j] = Blog[n = p*128 + tid/4][k = kt*64 + kh*32 + ((tid&3)^((tid>>3)&3))*8 + j]
// Swizzle s(row) = (row>>1)&3 (R6-verified: 2-way bank aliasing only, which is free).
__device__ __forceinline__ void wprep3_swz(const float* wr, const float* wi, bf16* W, int idx) {
    if (idx >= 2097152) return;
    int cls = idx >> 19;
    int r = idx & 524287;
    int e16 = r >> 3, j = r & 7;
    int tid = e16 & 511;
    int p = (e16 >> 9) & 1;
    int khh = (e16 >> 10) & 1;
    int kt = (e16 >> 11) & 31;
    int n = p * 128 + (tid >> 2);
    int cphys = tid & 3;
    int clog = cphys ^ ((tid >> 3) & 3);
    int k = kt * 64 + khh * 32 + clog * 8 + j;
    int c = n >> 1, part = n & 1;
    int t = k >> 9, q = k & 511;
    int ci = q >> 1, pk = q & 1;
    int py = cls >> 1, px = cls & 1;
    int a = t >> 1, e = t & 1;
    int kh_ = py ? (a ? 2 : 0) : (a ? 3 : 1);
    int kw_ = px ? (e ? 2 : 0) : (e ? 3 : 1);
    size_t widx = ((size_t)ci * C3 + c) * 16 + kh_ * 4 + kw_;
    float vr = wr[widx], vi = wi[widx];
    float v = (part == 0) ? (pk ? -vi : vr) : (pk ? vr : vi);
    W[idx] = f2b(v);
}

__device__ __forceinline__ void wprep4_body(const float* wr, const float* wi, bf16* W, int idx) {
    if (idx >= 65536) return;
    int cls = idx >> 14, rem = idx & 16383;
    int py = cls >> 1, px = cls & 1;
    int n = rem >> 10, k = rem & 1023;
    float v = 0.f;
    if (n < NCH) {
        int t = k >> 8, q = k & 255;
        int ci = q >> 1, p = q & 1;
        int a = t >> 1, e = t & 1;
        int kh = py ? (a ? 2 : 0) : (a ? 3 : 1);
        int kw = px ? (e ? 2 : 0) : (e ? 3 : 1);
        size_t widx = ((size_t)ci * NCH + n) * 16 + kh * 4 + kw;
        v = p ? -wi[widx] : wr[widx];
    }
    W[idx] = f2b(v);
}

__device__ __forceinline__ void x0_body(const float* nre, const float* nim,
                                        const int* labels, const float* emb,
                                        bf16* A, int idx) {
    if (idx >= BATCH * 224) return;
    int b = idx / 224, k = idx - b * 224;
    int p = k >= 112; int ci = k - p * 112;
    float v = 0.f;
    if (ci < CIN0) {
        if (!p) v = (ci < LAT) ? nre[b * LAT + ci] : emb[labels[b] * NCLS + (ci - LAT)];
        else    v = (ci < LAT) ? nim[b * LAT + ci] : 0.f;
    }
    A[idx] = f2b(v);
}

__global__ void prep_combined(const float* __restrict__ w1r, const float* __restrict__ w1i,
                              const float* __restrict__ w2r, const float* __restrict__ w2i,
                              const float* __restrict__ w3r, const float* __restrict__ w3i,
                              const float* __restrict__ w4r, const float* __restrict__ w4i,
                              const float* __restrict__ nre, const float* __restrict__ nim,
                              const int* __restrict__ labels, const float* __restrict__ emb,
                              bf16* __restrict__ B1, bf16* __restrict__ W2all,
                              bf16* __restrict__ W3all, bf16* __restrict__ W4all,
                              bf16* __restrict__ x0bf, float* __restrict__ Szero,
                              float* __restrict__ Zb) {
    int bid = blockIdx.x;
    if (bid < NB_W1) {
        w1prep_body(w1r, w1i, B1, bid * 256 + threadIdx.x);
    } else if (bid < NB_W1 + NB_W2) {
        wprep_panel_body<C1, C2>(w2r, w2i, W2all, (size_t)(bid - NB_W1) * 256 + threadIdx.x);
    } else if (bid < NB_W1 + NB_W2 + NB_W3) {
        wprep3_swz(w3r, w3i, W3all, (bid - NB_W1 - NB_W2) * 256 + threadIdx.x);
    } else if (bid < NB_W1 + NB_W2 + NB_W3 + NB_W4) {
        wprep4_body(w4r, w4i, W4all, (bid - NB_W1 - NB_W2 - NB_W3) * 256 + threadIdx.x);
    } else if (bid < NB_W1 + NB_W2 + NB_W3 + NB_W4 + NB_X0) {
        x0_body(nre, nim, labels, emb, x0bf,
                (bid - NB_W1 - NB_W2 - NB_W3 - NB_W4) * 256 + threadIdx.x);
    } else {
        int idx = (bid - NB_W1 - NB_W2 - NB_W3 - NB_W4 - NB_X0) * 256 + threadIdx.x;
        if (idx < 35840) Szero[idx] = 0.f;          // stat copies (143360 B)
        else if (idx < 36096) Zb[idx - 35840] = 0.f; // 1KB zero-page
    }
}

// ------- epilogue-stats: lq-shfl pre-reduce -> LDS -> atomics into sharded copy -------
__device__ __forceinline__ void epi_stats_flush(float* red, float* Scopy, int Cn,
                                                int cBaseGlobal, int tid, int lq,
                                                const int* clArr, float* s1,
                                                float* s2, float* sp, int isRe) {
    for (int i = tid; i < 320; i += 256) red[i] = 0.f;
    __syncthreads();
#pragma unroll
    for (int sn = 0; sn < 4; ++sn) {
        s1[sn] += __shfl_xor(s1[sn], 16, 64); s1[sn] += __shfl_xor(s1[sn], 32, 64);
        s2[sn] += __shfl_xor(s2[sn], 16, 64); s2[sn] += __shfl_xor(s2[sn], 32, 64);
        sp[sn] += __shfl_xor(sp[sn], 16, 64); sp[sn] += __shfl_xor(sp[sn], 32, 64);
    }
    if (lq == 0) {
#pragma unroll
        for (int sn = 0; sn < 4; ++sn) {
            int cl = clArr[sn];
            if (isRe) {
                atomicAdd(&red[cl * 5 + 0], s1[sn]);
                atomicAdd(&red[cl * 5 + 2], s2[sn]);
                atomicAdd(&red[cl * 5 + 4], sp[sn]);
            } else {
                atomicAdd(&red[cl * 5 + 1], s1[sn]);
                atomicAdd(&red[cl * 5 + 3], s2[sn]);
            }
        }
    }
    __syncthreads();
    for (int i = tid; i < 320; i += 256) {
        int cl = i / 5, st = i - cl * 5;
        atomicAdd(&Scopy[st * Cn + cBaseGlobal + cl], red[i]);
    }
}

// ---------------- gemm1 -> x1cl (interleaved), + BN1 stats ----------------
__global__ __launch_bounds__(256, 1) void gemm1(
    const bf16* __restrict__ A, const bf16* __restrict__ B,
    const float* __restrict__ b1r, const float* __restrict__ b1i,
    bf16* __restrict__ Y, float* __restrict__ Sstat) {
    __shared__ short As[128][40];
    __shared__ short Bs[128][40];
    const int tid = threadIdx.x;
    const int mBase = blockIdx.x * 128, nBase = blockIdx.y * 128;
    const int wid = tid >> 6, lane = tid & 63;
    const int wm = (wid >> 1) * 64, wn = (wid & 1) * 64;
    const int lm = lane & 15, lq = lane >> 4;

    f32x4 acc[4][4] = {};

    for (int k0 = 0; k0 < 224; k0 += 32) {
#pragma unroll
        for (int it = 0; it < 2; ++it) {
            int slot = tid + it * 256;
            int row = slot >> 2, kc = (slot & 3) * 8;
            int k = k0 + kc;
            *(uint4*)(&As[row][kc]) = *(const uint4*)(A + (size_t)(mBase + row) * 224 + k);
            *(uint4*)(&Bs[row][kc]) = *(const uint4*)(B + (size_t)(nBase + row) * 224 + k);
        }
        __syncthreads();
        bf16x8 af[4], bfr[4];
#pragma unroll
        for (int s = 0; s < 4; ++s) {
            af[s]  = *(const bf16x8*)(&As[wm + s * 16 + lm][lq * 8]);
            bfr[s] = *(const bf16x8*)(&Bs[wn + s * 16 + lm][lq * 8]);
        }
#pragma unroll
        for (int sm = 0; sm < 4; ++sm)
#pragma unroll
            for (int sn = 0; sn < 4; ++sn)
                acc[sm][sn] = __builtin_amdgcn_mfma_f32_16x16x32_bf16(af[sm], bfr[sn], acc[sm][sn], 0, 0, 0);
        __syncthreads();
    }

    float s1[4] = {}, s2[4] = {}, sp[4] = {};
    int clArr[4];
#pragma unroll
    for (int sn = 0; sn < 4; ++sn) clArr[sn] = (wn + sn * 16 + lm) >> 1;
    const int part = lm & 1;

#pragma unroll
    for (int sm = 0; sm < 4; ++sm) {
#pragma unroll
        for (int v = 0; v < 4; ++v) {
            int m = mBase + wm + sm * 16 + lq * 4 + v;
#pragma unroll
            for (int sn = 0; sn < 4; ++sn) {
                int n = nBase + wn + sn * 16 + lm;
                int c = (n & 1023) >> 1;
                float bias = part ? b1i[c] : b1r[c];
                float val = acc[sm][sn][v] + bias;
                float pv = __shfl_xor(val, 1, 64);
                s1[sn] += val; s2[sn] += val * val;
                if (!part) sp[sn] += val * pv;
                Y[(size_t)m * 16384 + n] = f2b(val);
            }
        }
    }
    int copy = (blockIdx.y * gridDim.x + blockIdx.x) & (NCOPY - 1);
    epi_stats_flush((float*)As, Sstat + (size_t)copy * 5 * C1, C1,
                    (nBase & 1023) >> 1, tid, lq, clArr, s1, s2, sp, !part);
}

// ------- BN apply+ReLU: block-cooperative fold of NCOPY stat copies -> LDS coefs -------
__global__ void bn_apply_v3(bf16* __restrict__ Y, const float* __restrict__ Scopies,
                            const float* __restrict__ grr, const float* __restrict__ gri,
                            const float* __restrict__ gii,
                            const float* __restrict__ betar, const float* __restrict__ betai,
                            int C, int total8, float invN) {
    __shared__ float coefs[6][512];
    for (int c = threadIdx.x; c < C; c += 256) {
        float sr = 0, si = 0, srr = 0, sii = 0, sri = 0;
        for (int cp = 0; cp < NCOPY; ++cp) {
            const float* S = Scopies + (size_t)cp * 5 * C;
            sr += S[c]; si += S[C + c]; srr += S[2 * C + c]; sii += S[3 * C + c]; sri += S[4 * C + c];
        }
        float mr = sr * invN, mi = si * invN;
        float crr = srr * invN - mr * mr + EPS;
        float cii = sii * invN - mi * mi + EPS;
        float cri = sri * invN - mr * mi;
        float s = sqrtf(crr * cii - cri * cri);
        float t = sqrtf(crr + cii + 2.f * s);
        float inv = 1.f / (s * t);
        float rrr = (cii + s) * inv, rii = (crr + s) * inv, rri = -cri * inv;
        float Grr = grr[c], Gri = gri[c], Gii = gii[c];
        float arr = Grr * rrr + Gri * rri, ari = Grr * rri + Gri * rii;
        float air = Gri * rrr + Gii * rri, aii = Gri * rri + Gii * rii;
        coefs[0][c] = arr; coefs[1][c] = ari;
        coefs[2][c] = betar[c] - arr * mr - ari * mi;
        coefs[3][c] = air; coefs[4][c] = aii;
        coefs[5][c] = betai[c] - air * mr - aii * mi;
    }
    __syncthreads();
    int idx = blockIdx.x * 256 + threadIdx.x;
    if (idx >= total8) return;
    size_t base = (size_t)idx * 8;
    int c0 = ((int)(base & (size_t)(2 * C - 1))) >> 1;
    bf16x8 v8 = *(const bf16x8*)(Y + base);
    bf16x8 o8;
#pragma unroll
    for (int u = 0; u < 4; ++u) {
        int c = c0 + u;
        float vr = s2f(v8[2 * u]), vi = s2f(v8[2 * u + 1]);
        o8[2 * u]     = f2s(fmaxf(coefs[0][c] * vr + coefs[1][c] * vi + coefs[2][c], 0.f));
        o8[2 * u + 1] = f2s(fmaxf(coefs[3][c] * vr + coefs[4][c] * vi + coefs[5][c], 0.f));
    }
    *(bf16x8*)(Y + base) = o8;
}

// ---------------- L2: MFMA GEMM 128x128, BK=64 (R2 structure, unchanged) ----------------
template<int CIN, int S, int N>
__global__ __launch_bounds__(256, 3) void gemm_convt_bd(
    const bf16* __restrict__ X, const bf16* __restrict__ Wall,
    const float* __restrict__ biasr, const float* __restrict__ biasi,
    bf16* __restrict__ Y, float* __restrict__ Sstat) {
    constexpr int TWOK = 8 * CIN, C2I = 2 * CIN, C2O = 2 * N, HOUT = 2 * S;
    constexpr int NSTEP = TWOK / 64;
    constexpr int CPS32 = C2I / 32;
    constexpr int LOG_CPS = (CIN == 512) ? 5 : 4;
    constexpr int GX = (BATCH * S * S) / 128;
    constexpr int GY = C2O / 128;
    constexpr int GZ = 4;
    constexpr int NWG = GX * GY * GZ;
    constexpr int CHUNK = NWG / 8;
    constexpr int NYZ = GY * GZ;
    __shared__ short As[2][2][128][40];

    const int phys = (blockIdx.z * GY + blockIdx.y) * GX + blockIdx.x;
    const int L = (phys & 7) * CHUNK + (phys >> 3);
    const int bx = L / NYZ;
    const int ryz = L - bx * NYZ;
    const int by = ryz % GY;
    const int bz = ryz / GY;

    const int cls = bz;
    const int py = cls >> 1, px = cls & 1;
    const int tid = threadIdx.x;
    const int mBase = bx * 128, nBase = by * 128;
    const int wid = tid >> 6, lane = tid & 63;
    const int wm = (wid >> 1) * 64, wn = (wid & 1) * 64;
    const int lm = lane & 15, lq = lane >> 4;
    const int dh0 = py ? 1 : 0, dh1 = py ? 0 : -1;
    const int dw0 = px ? 1 : 0, dw1 = px ? 0 : -1;

    const bf16* Wp = Wall
        + ((size_t)(cls * (C2O / 128) + by) * (TWOK / 32)) * 4096
        + ((wn >> 6) * 4) * 512 + lane * 8;

    int rowA[2], kcA[2];
    int offT[2][4];
#pragma unroll
    for (int j = 0; j < 2; ++j) {
        int slot = tid + j * 256;
        rowA[j] = slot >> 2; kcA[j] = (slot & 3) * 8;
        int m = mBase + rowA[j];
        int b = m / (S * S); int rem = m - b * (S * S);
        int i = rem / S, jj = rem % S;
#pragma unroll
        for (int t = 0; t < 4; ++t) {
            int a = t >> 1, e = t & 1;
            int ih = i + (a ? dh1 : dh0);
            int iw = jj + (e ? dw1 : dw0);
            offT[j][t] = ((unsigned)ih < (unsigned)S && (unsigned)iw < (unsigned)S)
                ? ((b * S + ih) * S + iw) * C2I : -1;
        }
    }

    auto loadA = [&](int ksn, uint4* av) {
        int kb0 = 2 * ksn;
        int t = kb0 >> LOG_CPS;
        int q0 = (kb0 & (CPS32 - 1)) << 5;
#pragma unroll
        for (int it = 0; it < 4; ++it) {
            int j = it & 1, h = it >> 1;
            int o = offT[j][t];
            uint4 v = {0u, 0u, 0u, 0u};
            if (o >= 0)
                v = *(const uint4*)(X + (size_t)o + q0 + h * 32 + kcA[j]);
            av[it] = v;
        }
    };

    f32x4 acc[4][4] = {};
    bf16x8 bA[4];

    {
        uint4 a0[4];
        loadA(0, a0);
#pragma unroll
        for (int sn = 0; sn < 4; ++sn) bA[sn] = *(const bf16x8*)(Wp + sn * 512);
#pragma unroll
        for (int it = 0; it < 4; ++it)
            *(uint4*)(&As[0][it >> 1][rowA[it & 1]][kcA[it & 1]]) = a0[it];
    }
    __syncthreads();

    for (int ks = 0; ks < NSTEP; ++ks) {
        const int cur = ks & 1;
        const bool hasNext = (ks + 1 < NSTEP);
        uint4 aS[4];
        if (hasNext) loadA(ks + 1, aS);
        bf16x8 bB[4];
        {
            const bf16* W1 = Wp + (size_t)(2 * ks + 1) * 4096;
#pragma unroll
            for (int sn = 0; sn < 4; ++sn) bB[sn] = *(const bf16x8*)(W1 + sn * 512);
        }
        {
            bf16x8 af[4];
#pragma unroll
            for (int s = 0; s < 4; ++s)
                af[s] = *(const bf16x8*)(&As[cur][0][wm + s * 16 + lm][lq * 8]);
#pragma unroll
            for (int sm = 0; sm < 4; ++sm)
#pragma unroll
                for (int sn = 0; sn < 4; ++sn)
                    acc[sm][sn] = __builtin_amdgcn_mfma_f32_16x16x32_bf16(af[sm], bA[sn], acc[sm][sn], 0, 0, 0);
        }
        if (hasNext) {
            const bf16* W2 = Wp + (size_t)(2 * ks + 2) * 4096;
#pragma unroll
            for (int sn = 0; sn < 4; ++sn) bA[sn] = *(const bf16x8*)(W2 + sn * 512);
        }
        {
            bf16x8 af[4];
#pragma unroll
            for (int s = 0; s < 4; ++s)
                af[s] = *(const bf16x8*)(&As[cur][1][wm + s * 16 + lm][lq * 8]);
#pragma unroll
            for (int sm = 0; sm < 4; ++sm)
#pragma unroll
                for (int sn = 0; sn < 4; ++sn)
                    acc[sm][sn] = __builtin_amdgcn_mfma_f32_16x16x32_bf16(af[sm], bB[sn], acc[sm][sn], 0, 0, 0);
        }
        if (hasNext) {
#pragma unroll
            for (int it = 0; it < 4; ++it)
                *(uint4*)(&As[1 - cur][it >> 1][rowA[it & 1]][kcA[it & 1]]) = aS[it];
        }
        __syncthreads();
    }

    float s1[4] = {}, s2[4] = {}, sp[4] = {};
    int clArr[4];
#pragma unroll
    for (int sn = 0; sn < 4; ++sn) clArr[sn] = (wn + sn * 16 + lm) >> 1;
    const int part = lm & 1;

#pragma unroll
    for (int sm = 0; sm < 4; ++sm) {
#pragma unroll
        for (int v = 0; v < 4; ++v) {
            int m = mBase + wm + sm * 16 + lq * 4 + v;
            int b = m / (S * S); int rem = m - b * (S * S);
            int i = rem / S, j = rem % S;
            int oh = 2 * i + py, ow = 2 * j + px;
            size_t rowoff = (size_t)((b * HOUT + oh) * HOUT + ow) * C2O;
#pragma unroll
            for (int sn = 0; sn < 4; ++sn) {
                int n = nBase + wn + sn * 16 + lm;
                int c = n >> 1;
                float bias = part ? biasi[c] : biasr[c];
                float val = acc[sm][sn][v] + bias;
                float pv = __shfl_xor(val, 1, 64);
                s1[sn] += val; s2[sn] += val * val;
                if (!part) sp[sn] += val * pv;
                Y[rowoff + n] = f2b(val);
            }
        }
    }
    int copy = L & (NCOPY - 1);
    epi_stats_flush((float*)As, Sstat + (size_t)copy * 5 * N, N,
                    nBase >> 1, tid, lq, clArr, s1, s2, sp, !part);
}

// ---------------- L3: 256x256 8-wave counted-vmcnt template (m201 geometry) ----------------
// R7: R6 proved the two R5 defects fixed (swizzle -> no conflicts; no spill) but at 128x256
// the staging economy is 1.5x worse than m201 (11.4 KB/MFLOP, 3 DMA issues/phase). This is
// the 256x256 retry with both fixes: 7.6 KB/MFLOP, exactly 2 DMA issues/thread/phase,
// grid 256 = 1 block/CU. acc[8][4] = 128 AGPRs; #pragma unroll 1 epilogue keeps arch VGPRs
// ~100 <= 128 (the (512,2) arch budget after the AGPR split -- R5's spill model).
// vmcnt(4) at phases 1,3 only (4 loads always in flight); vmcnt(0) only in peeled kt=31.
#define DSRD_A(PAR, MH, KS, AF) do {                                                    \
    _Pragma("unroll")                                                                   \
    for (int s = 0; s < 4; ++s)                                                         \
        AF[s] = *(const bf16x8*)(LDSm + (PAR) * 16384 + (KS) * 8192                     \
                                 + (wm + (MH) * 64 + s * 16 + lm) * 32 + ardq);         \
} while (0)
#define DSRD_B(PAR, KS, BV) do {                                                        \
    _Pragma("unroll")                                                                   \
    for (int sn = 0; sn < 4; ++sn)                                                      \
        BV[sn] = *(const bf16x8*)(LDSm + 32768 + (PAR) * 16384 + (KS) * 8192            \
                                  + (wn + sn * 16 + lm) * 32 + ardq);                   \
} while (0)
#define MFMA16(MH, AF, BV) do {                                                         \
    __builtin_amdgcn_s_setprio(1);                                                      \
    _Pragma("unroll")                                                                   \
    for (int s = 0; s < 4; ++s)                                                         \
        _Pragma("unroll")                                                               \
        for (int sn = 0; sn < 4; ++sn)                                                  \
            acc[(MH) * 4 + s][sn] = __builtin_amdgcn_mfma_f32_16x16x32_bf16(            \
                AF[s], BV[sn], acc[(MH) * 4 + s][sn], 0, 0, 0);                         \
    __builtin_amdgcn_s_setprio(0);                                                      \
} while (0)
#define MEMFENCE asm volatile("" ::: "memory")

__global__ __launch_bounds__(512, 2) void gemm3_8ph(
    const bf16* __restrict__ X, const bf16* __restrict__ Wall,
    const float* __restrict__ biasr, const float* __restrict__ biasi,
    bf16* __restrict__ Y, float* __restrict__ Sstat,
    const bf16* __restrict__ zb) {
    constexpr int C2I = 512, C2O = 256;
    __shared__ short LDSm[65536];          // 128KB: A bytes [0,65536), B bytes [65536,131072)
    char* ldsB = (char*)LDSm;

    const int tid = threadIdx.x;
    const int phys = blockIdx.x;
    const int L = (phys & 7) * 32 + (phys >> 3);   // XCD swizzle: 8 bx-panels x 4 cls per XCD
    const int bx = L >> 2, cls = L & 3;
    const int py = cls >> 1, px = cls & 1;
    const int mBase = bx * 256;
    const int wid = tid >> 6, lane = tid & 63;
    const int wm = (wid >> 2) * 128;       // 2 M-waves (128 rows each)
    const int wn = (wid & 3) * 64;         // 4 N-waves
    const int lm = lane & 15, lq = lane >> 4;
    const int dh0 = py ? 1 : 0, dh1 = py ? 0 : -1;
    const int dw0 = px ? 1 : 0, dw1 = px ? 0 : -1;

    const bf16* Wsrc = Wall + (size_t)cls * 524288 + tid * 8;
    const int zoff = (int)(zb - X);

    // A staging: issue p covers rows p*128 + tid/4 (4 threads x 16B per 64B row-half).
    const int cgA = ((tid & 3) ^ ((tid >> 3) & 3)) * 8;   // inverse-swizzled source chunk
    int bP[2], iP[2], jP[2];
#pragma unroll
    for (int p = 0; p < 2; ++p) {
        int m = mBase + p * 128 + (tid >> 2);
        bP[p] = m >> 6; int rem = m & 63; iP[p] = rem >> 3; jP[p] = rem & 7;
    }
    // ds_read physical chunk: lq ^ ((row>>1)&3), row&15==lm for all fragments.
    const int ardq = (lq ^ ((lm >> 1) & 3)) * 8;

    f32x4 acc[8][4] = {};

    auto eoCalc = [&](int tp, int* eo) {
        int a = tp >> 1, e = tp & 1;
        int dh = a ? dh1 : dh0, dw = e ? dw1 : dw0;
#pragma unroll
        for (int p = 0; p < 2; ++p) {
            int ih = iP[p] + dh, iw = jP[p] + dw;
            eo[p] = ((unsigned)ih < 8u && (unsigned)iw < 8u)
                ? ((bP[p] * 8 + ih) * 8 + iw) * C2I : zoff;
        }
    };

    {   // prologue: stage kt=0 (par 0) in order {A-kh0 x2, B-kh0 x2, A-kh1 x2, B-kh1 x2}
        int eo0[2];
        eoCalc(0, eo0);
#pragma unroll
        for (int kh = 0; kh < 2; ++kh) {
#pragma unroll
            for (int p = 0; p < 2; ++p)
                gl_lds16(X + eo0[p] + kh * 32 + cgA,
                         ldsB + kh * 16384 + p * 8192 + tid * 16);
            MEMFENCE;
#pragma unroll
            for (int p = 0; p < 2; ++p)
                gl_lds16(Wsrc + (size_t)(kh * 2 + p) * 4096,
                         ldsB + 65536 + kh * 16384 + p * 8192 + tid * 16);
            MEMFENCE;
        }
        asm volatile("s_waitcnt vmcnt(4)" ::: "memory");
        __builtin_amdgcn_s_barrier();
    }

#pragma unroll 1
    for (int kt = 0; kt < 31; ++kt) {
        const int par = kt & 1;
        int eoN[2];
        eoCalc((kt + 1) >> 3, eoN);
        const int kcol = ((kt + 1) & 7) * 64;
        char* dstA = ldsB + (par ^ 1) * 32768;
        char* dstB = ldsB + 65536 + (par ^ 1) * 32768;
        bf16x8 af[4], bfv[4];
        // ph0: (mh0, ks0); stage A-kh0 of kt+1
        DSRD_A(par, 0, 0, af); DSRD_B(par, 0, bfv);
#pragma unroll
        for (int p = 0; p < 2; ++p)
            gl_lds16(X + eoN[p] + kcol + cgA, dstA + p * 8192 + tid * 16);
        MEMFENCE;
        __builtin_amdgcn_s_barrier();
        MFMA16(0, af, bfv);
        __builtin_amdgcn_s_barrier();
        MEMFENCE;
        // ph1: (mh1, ks0); stage B-kh0 of kt+1
        DSRD_A(par, 1, 0, af);
#pragma unroll
        for (int p = 0; p < 2; ++p)
            gl_lds16(Wsrc + (size_t)(((kt + 1) * 2 + 0) * 2 + p) * 4096,
                     dstB + p * 8192 + tid * 16);
        MEMFENCE;
        __builtin_amdgcn_s_barrier();
        MFMA16(1, af, bfv);
        asm volatile("s_waitcnt vmcnt(4)" ::: "memory");
        __builtin_amdgcn_s_barrier();
        MEMFENCE;
        // ph2: (mh0, ks1); stage A-kh1 of kt+1
        DSRD_A(par, 0, 1, af); DSRD_B(par, 1, bfv);
#pragma unroll
        for (int p = 0; p < 2; ++p)
            gl_lds16(X + eoN[p] + kcol + 32 + cgA, dstA + 16384 + p * 8192 + tid * 16);
        MEMFENCE;
        __builtin_amdgcn_s_barrier();
        MFMA16(0, af, bfv);
        __builtin_amdgcn_s_barrier();
        MEMFENCE;
        // ph3: (mh1, ks1); stage B-kh1 of kt+1
        DSRD_A(par, 1, 1, af);
#pragma unroll
        for (int p = 0; p < 2; ++p)
            gl_lds16(Wsrc + (size_t)(((kt + 1) * 2 + 1) * 2 + p) * 4096,
                     dstB + 16384 + p * 8192 + tid * 16);
        MEMFENCE;
        __builtin_amdgcn_s_barrier();
        MFMA16(1, af, bfv);
        asm volatile("s_waitcnt vmcnt(4)" ::: "memory");
        __builtin_amdgcn_s_barrier();
        MEMFENCE;
    }
    {   // peeled kt=31 (par=1): no staging; drain kh1's 4 in-flight loads before ph2 reads.
        bf16x8 af[4], bfv[4];
        DSRD_A(1, 0, 0, af); DSRD_B(1, 0, bfv);
        __builtin_amdgcn_s_barrier();
        MFMA16(0, af, bfv);
        __builtin_amdgcn_s_barrier();
        DSRD_A(1, 1, 0, af);
        __builtin_amdgcn_s_barrier();
        MFMA16(1, af, bfv);
        asm volatile("s_waitcnt vmcnt(0)" ::: "memory");
        __builtin_amdgcn_s_barrier();
        MEMFENCE;
        DSRD_A(1, 0, 1, af); DSRD_B(1, 1, bfv);
        __builtin_amdgcn_s_barrier();
        MFMA16(0, af, bfv);
        __builtin_amdgcn_s_barrier();
        DSRD_A(1, 1, 1, af);
        __builtin_amdgcn_s_barrier();
        MFMA16(1, af, bfv);
        __builtin_amdgcn_s_barrier();
    }

    __syncthreads();

    float s1[4] = {}, s2[4] = {}, sp[4] = {};
    int clArr[4];
#pragma unroll
    for (int sn = 0; sn < 4; ++sn) clArr[sn] = (wn + sn * 16 + lm) >> 1;
    const int part = lm & 1;

    // unroll 1: keep one sm-iteration's addresses live -> arch VGPRs stay under the
    // 128 cap (R5's fully-unrolled epilogue hoisted 32 rowoffs and spilled ~22 regs).
#pragma unroll 1
    for (int sm = 0; sm < 8; ++sm) {
#pragma unroll
        for (int v = 0; v < 4; ++v) {
            int m = mBase + wm + sm * 16 + lq * 4 + v;
            int b = m >> 6; int rem = m & 63;
            int i = rem >> 3, j = rem & 7;
            int oh = 2 * i + py, ow = 2 * j + px;
            size_t rowoff = (size_t)((b * 16 + oh) * 16 + ow) * C2O;
#pragma unroll
            for (int sn = 0; sn < 4; ++sn) {
                int n = wn + sn * 16 + lm;
                int c = n >> 1;
                float bias = part ? biasi[c] : biasr[c];
                float val = acc[sm][sn][v] + bias;
                float pv = __shfl_xor(val, 1, 64);
                s1[sn] += val; s2[sn] += val * val;
                if (!part) sp[sn] += val * pv;
                Y[rowoff + n] = f2b(val);
            }
        }
    }
    // stats flush: 128 channels x 5 stats = 640 slots
    float* red = (float*)(&LDSm[0]);
    for (int i2 = tid; i2 < 640; i2 += 512) red[i2] = 0.f;
    __syncthreads();
#pragma unroll
    for (int sn = 0; sn < 4; ++sn) {
        s1[sn] += __shfl_xor(s1[sn], 16, 64); s1[sn] += __shfl_xor(s1[sn], 32, 64);
        s2[sn] += __shfl_xor(s2[sn], 16, 64); s2[sn] += __shfl_xor(s2[sn], 32, 64);
        sp[sn] += __shfl_xor(sp[sn], 16, 64); sp[sn] += __shfl_xor(sp[sn], 32, 64);
    }
    if (lq == 0) {
#pragma unroll
        for (int sn = 0; sn < 4; ++sn) {
            int cl = clArr[sn];
            if (!part) {
                atomicAdd(&red[cl * 5 + 0], s1[sn]);
                atomicAdd(&red[cl * 5 + 2], s2[sn]);
                atomicAdd(&red[cl * 5 + 4], sp[sn]);
            } else {
                atomicAdd(&red[cl * 5 + 1], s1[sn]);
                atomicAdd(&red[cl * 5 + 3], s2[sn]);
            }
        }
    }
    __syncthreads();
    float* Sc = Sstat + (size_t)(L & (NCOPY - 1)) * 5 * 128;
    for (int i2 = tid; i2 < 640; i2 += 512) {
        int cl = i2 / 5, st = i2 - cl * 5;
        atomicAdd(&Sc[st * 128 + cl], red[i2]);
    }
}

// ---------------- layer4 via MFMA, M-tile 256, LDS-staged ----------------
__global__ __launch_bounds__(256, 2) void conv4_mfma(
    const bf16* __restrict__ X, const bf16* __restrict__ Wall,
    const float* __restrict__ br, float* __restrict__ out) {
    constexpr int S = 16, TWOK = 1024, C2I = 256;
    constexpr int GX = 256, GZ = 4, NWG = GX * GZ, CHUNK = NWG / 8;
    __shared__ short As[256][40];
    __shared__ short Bs[16][40];

    const int phys = blockIdx.z * GX + blockIdx.x;
    const int L = (phys & 7) * CHUNK + (phys >> 3);
    const int bx = L >> 2;
    const int cls = L & 3;

    const int py = cls >> 1, px = cls & 1;
    const bf16* W = Wall + (size_t)cls * 16 * TWOK;
    const int tid = threadIdx.x;
    const int mBase = bx * 256;
    const int wid = tid >> 6, lane = tid & 63;
    const int wm = wid * 64;
    const int lm = lane & 15, lq = lane >> 4;
    const int dh0 = py ? 1 : 0, dh1 = py ? 0 : -1;
    const int dw0 = px ? 1 : 0, dw1 = px ? 0 : -1;

    int rowA[4], kcA[4];
    long offT[4][4];
#pragma unroll
    for (int it = 0; it < 4; ++it) {
        int slot = tid + it * 256;
        rowA[it] = slot >> 2; kcA[it] = (slot & 3) * 8;
        int m = mBase + rowA[it];
        int b = m >> 8; int rem = m & 255;
        int i = rem >> 4, j = rem & 15;
#pragma unroll
        for (int t = 0; t < 4; ++t) {
            int a = t >> 1, e = t & 1;
            int ih = i + (a ? dh1 : dh0);
            int iw = j + (e ? dw1 : dw0);
            offT[it][t] = ((unsigned)ih < (unsigned)S && (unsigned)iw < (unsigned)S)
                ? (long)((b * S + ih) * S + iw) * C2I : -1L;
        }
    }

    f32x4 acc[4] = {};

    for (int kb = 0; kb < TWOK / 32; ++kb) {
        int t = kb >> 3;
        int q0 = (kb & 7) << 5;
#pragma unroll
        for (int it = 0; it < 4; ++it) {
            long o = offT[it][t];
            uint4 v = {0u, 0u, 0u, 0u};
            if (o >= 0)
                v = *(const uint4*)(X + o + q0 + kcA[it]);
            *(uint4*)(&As[rowA[it]][kcA[it]]) = v;
        }
        if (tid < 64) {
            int row = tid >> 2, kc = (tid & 3) * 8;
            uint4 w = *(const uint4*)(W + (size_t)row * TWOK + kb * 32 + kc);
            *(uint4*)(&Bs[row][kc]) = w;
        }
        __syncthreads();
        bf16x8 bfr = *(const bf16x8*)(&Bs[lm][lq * 8]);
#pragma unroll
        for (int s = 0; s < 4; ++s) {
            bf16x8 af = *(const bf16x8*)(&As[wm + s * 16 + lm][lq * 8]);
            acc[s] = __builtin_amdgcn_mfma_f32_16x16x32_bf16(af, bfr, acc[s], 0, 0, 0);
        }
        __syncthreads();
    }

    int n = lm;
    if (n < NCH) {
        float bias = br[n];
#pragma unroll
        for (int s = 0; s < 4; ++s) {
#pragma unroll
            for (int v = 0; v < 4; ++v) {
                int m = mBase + wm + s * 16 + lq * 4 + v;
                int b = m >> 8; int rem = m & 255;
                int i = rem >> 4, j = rem & 15;
                int oh = 2 * i + py, ow = 2 * j + px;
                out[((size_t)(b * NCH + n) * 32 + oh) * 32 + ow] = tanhf(acc[s][v] + bias);
            }
        }
    }
}

extern "C" void kernel_launch(void* const* d_in, const int* in_sizes, int n_in,
                              void* d_out, int out_size, void* d_ws, size_t ws_size,
                              hipStream_t stream) {
    const float* noise_re = (const float*)d_in[0];
    const float* noise_im = (const float*)d_in[1];
    const int*   labels   = (const int*)d_in[2];
    const float* emb      = (const float*)d_in[3];
    const float* w1r = (const float*)d_in[4],  *w1i = (const float*)d_in[5];
    const float* b1r = (const float*)d_in[6],  *b1i = (const float*)d_in[7];
    const float* g1rr = (const float*)d_in[8], *g1ri = (const float*)d_in[9], *g1ii = (const float*)d_in[10];
    const float* n1br = (const float*)d_in[11], *n1bi = (const float*)d_in[12];
    const float* w2r = (const float*)d_in[13], *w2i = (const float*)d_in[14];
    const float* b2r = (const float*)d_in[15], *b2i = (const float*)d_in[16];
    const float* g2rr = (const float*)d_in[17], *g2ri = (const float*)d_in[18], *g2ii = (const float*)d_in[19];
    const float* n2br = (const float*)d_in[20], *n2bi = (const float*)d_in[21];
    const float* w3r = (const float*)d_in[22], *w3i = (const float*)d_in[23];
    const float* b3r = (const float*)d_in[24], *b3i = (const float*)d_in[25];
    const float* g3rr = (const float*)d_in[26], *g3ri = (const float*)d_in[27], *g3ii = (const float*)d_in[28];
    const float* n3br = (const float*)d_in[29], *n3bi = (const float*)d_in[30];
    const float* w4r = (const float*)d_in[31], *w4i = (const float*)d_in[32];
    const float* b4r = (const float*)d_in[33], *b4i = (const float*)d_in[34];

    // ---- workspace layout (bytes) ----
    char* ws = (char*)d_ws;
    bf16* y3cl = (bf16*)ws;
    bf16* x1cl = (bf16*)ws;
    bf16* B1    = (bf16*)(ws + 8388608);
    bf16* W2all = (bf16*)(ws + 15728640);
    bf16* y2cl  = (bf16*)(ws + 33554432);
    bf16* W3all = (bf16*)(ws + 50331648);
    bf16* x0bf  = (bf16*)(ws + 54547456);
    bf16* W4all = (bf16*)(ws + 54662144);
    float* S1 = (float*)(ws + 54793216);
    float* S2 = (float*)(ws + 54875136);
    float* S3 = (float*)(ws + 54916096);
    // 1KB zero-page in the unused gap between W3all end (54525952) and x0bf (54547456)
    float* Zb = (float*)(ws + 54526976);

    prep_combined<<<NB_W1 + NB_W2 + NB_W3 + NB_W4 + NB_X0 + NB_Z, 256, 0, stream>>>(
        w1r, w1i, w2r, w2i, w3r, w3i, w4r, w4i,
        noise_re, noise_im, labels, emb,
        B1, W2all, W3all, W4all, x0bf, S1, Zb);

    // L1 GEMM (+BN1 stats, sharded) -> x1cl
    gemm1<<<dim3(2, 128), 256, 0, stream>>>(x0bf, B1, b1r, b1i, x1cl, S1);
    bn_apply_v3<<<2048, 256, 0, stream>>>(x1cl, S1, g1rr, g1ri, g1ii, n1br, n1bi,
                                          C1, 524288, 1.f / 4096.f);

    // L2 GEMM (+BN2 stats) -> y2cl
    gemm_convt_bd<C1, 4, C2><<<dim3(32, 4, 4), 256, 0, stream>>>(x1cl, W2all, b2r, b2i, y2cl, S2);
    bn_apply_v3<<<4096, 256, 0, stream>>>(y2cl, S2, g2rr, g2ri, g2ii, n2br, n2bi,
                                          C2, 1048576, 1.f / 16384.f);

    // L3 GEMM (+BN3 stats) -> y3cl : 256x256 8-wave counted-vmcnt schedule (A+B via LDS)
    gemm3_8ph<<<dim3(256), 512, 0, stream>>>(y2cl, W3all, b3r, b3i, y3cl, S3,
                                             (const bf16*)Zb);
    bn_apply_v3<<<8192, 256, 0, stream>>>(y3cl, S3, g3rr, g3ri, g3ii, n3br, n3bi,
                                          C3, 2097152, 1.f / 65536.f);

    // L4: MFMA + tanh -> d_out (real part, fp32), M-tile 256
    conv4_mfma<<<dim3(256, 1, 4), 256, 0, stream>>>(y3cl, W4all, b4r, (float*)d_out);
}

// Round 8
// 457.017 us; speedup vs baseline: 1.0981x; 1.0981x over previous
//
#include <hip/hip_runtime.h>
#include <hip/hip_bf16.h>
#include <math.h>

#define BATCH 256
#define LAT 100
#define NCLS 10
#define CIN0 110
#define C1 512
#define C2 256
#define C3 128
#define NCH 3
#define EPS 1e-5f
#define NCOPY 8

typedef __hip_bfloat16 bf16;
typedef short bf16x8 __attribute__((ext_vector_type(8)));
typedef float f32x4 __attribute__((ext_vector_type(4)));

__device__ __forceinline__ float b2f(bf16 v) { return __bfloat162float(v); }
__device__ __forceinline__ bf16 f2b(float v) { return __float2bfloat16(v); }
__device__ __forceinline__ float s2f(short s) {
    unsigned u = ((unsigned)(unsigned short)s) << 16;
    return __builtin_bit_cast(float, u);
}
__device__ __forceinline__ short f2s(float f) {
    bf16 b = __float2bfloat16(f);
    return *(short*)&b;
}

__device__ __forceinline__ void gl_lds16(const void* g, void* l) {
    __builtin_amdgcn_global_load_lds(
        (__attribute__((address_space(1))) const void*)g,
        (__attribute__((address_space(3))) void*)l, 16, 0, 0);
}

// ======== INTERLEAVED complex channel layout everywhere ========
#define NB_W1 14336
#define NB_W2 32768
#define NB_W3 8192
#define NB_W4 256
#define NB_X0 224
#define NB_Z  141    // zero stat copies (35840 f) + 1KB zero-page for gload_lds OOB taps

__device__ __forceinline__ void w1prep_body(const float* wr, const float* wi, bf16* B, int idx) {
    if (idx >= 16384 * 224) return;
    int n = idx / 224, k = idx - n * 224;
    int p = n >> 10;
    int c = (n & 1023) >> 1;
    int part = n & 1;
    int pk = k >= 112; int ci = k - pk * 112;
    float v = 0.f;
    if (ci < CIN0) {
        size_t widx = ((size_t)ci * C1 + c) * 16 + p;
        float vr = wr[widx], vi = wi[widx];
        v = (part == 0) ? (pk ? -vi : vr) : (pk ? vr : vi);
    }
    B[idx] = f2b(v);
}

template<int CIN, int N>
__device__ __forceinline__ void wprep_panel_body(const float* wr, const float* wi, bf16* W,
                                                 size_t idx) {
    constexpr int TWOK = 8 * CIN, C2I = 2 * CIN;
    size_t per_cls = (size_t)2 * N * TWOK;
    if (idx >= 4 * per_cls) return;
    int cls = (int)(idx / per_cls);
    size_t r = idx - (size_t)cls * per_cls;
    size_t chunk_nb = (size_t)TWOK * 128;
    int nb = (int)(r / chunk_nb);
    int r2 = (int)(r - (size_t)nb * chunk_nb);
    int kb = r2 >> 12;
    int w = r2 & 4095;
    int f = w >> 9;
    int l = (w >> 3) & 63;
    int j = w & 7;
    int n_virt = nb * 128 + (f >> 2) * 64 + (f & 3) * 16 + (l & 15);
    int k = kb * 32 + (l >> 4) * 8 + j;
    int c = n_virt >> 1, part = n_virt & 1;
    int t = k / C2I;
    int q = k & (C2I - 1);
    int ci = q >> 1, p = q & 1;
    int py = cls >> 1, px = cls & 1;
    int a = t >> 1, e = t & 1;
    int kh = py ? (a ? 2 : 0) : (a ? 3 : 1);
    int kw = px ? (e ? 2 : 0) : (e ? 3 : 1);
    size_t widx = ((size_t)ci * N + c) * 16 + kh * 4 + kw;
    float vr = wr[widx], vi = wi[widx];
    float v = (part == 0) ? (p ? -vi : vr) : (p ? vr : vi);
    W[idx] = f2b(v);
}

// W3S: pre-swizzled staging layout for gemm3_8ph's B tiles. Linear-source staging:
// W3S[cls][kt][kh][p][tid][j] = Blog[n = p*128 + tid/4][k = kt*64 + kh*32 + ((tid&3)^((tid>>3)&3))*8 + j]
// Swizzle s(row) = (row>>1)&3 (R6-verified: 2-way bank aliasing only, which is free).
__device__ __forceinline__ void wprep3_swz(const float* wr, const float* wi, bf16* W, int idx) {
    if (idx >= 2097152) return;
    int cls = idx >> 19;
    int r = idx & 524287;
    int e16 = r >> 3, j = r & 7;
    int tid = e16 & 511;
    int p = (e16 >> 9) & 1;
    int khh = (e16 >> 10) & 1;
    int kt = (e16 >> 11) & 31;
    int n = p * 128 + (tid >> 2);
    int cphys = tid & 3;
    int clog = cphys ^ ((tid >> 3) & 3);
    int k = kt * 64 + khh * 32 + clog * 8 + j;
    int c = n >> 1, part = n & 1;
    int t = k >> 9, q = k & 511;
    int ci = q >> 1, pk = q & 1;
    int py = cls >> 1, px = cls & 1;
    int a = t >> 1, e = t & 1;
    int kh_ = py ? (a ? 2 : 0) : (a ? 3 : 1);
    int kw_ = px ? (e ? 2 : 0) : (e ? 3 : 1);
    size_t widx = ((size_t)ci * C3 + c) * 16 + kh_ * 4 + kw_;
    float vr = wr[widx], vi = wi[widx];
    float v = (part == 0) ? (pk ? -vi : vr) : (pk ? vr : vi);
    W[idx] = f2b(v);
}

__device__ __forceinline__ void wprep4_body(const float* wr, const float* wi, bf16* W, int idx) {
    if (idx >= 65536) return;
    int cls = idx >> 14, rem = idx & 16383;
    int py = cls >> 1, px = cls & 1;
    int n = rem >> 10, k = rem & 1023;
    float v = 0.f;
    if (n < NCH) {
        int t = k >> 8, q = k & 255;
        int ci = q >> 1, p = q & 1;
        int a = t >> 1, e = t & 1;
        int kh = py ? (a ? 2 : 0) : (a ? 3 : 1);
        int kw = px ? (e ? 2 : 0) : (e ? 3 : 1);
        size_t widx = ((size_t)ci * NCH + n) * 16 + kh * 4 + kw;
        v = p ? -wi[widx] : wr[widx];
    }
    W[idx] = f2b(v);
}

__device__ __forceinline__ void x0_body(const float* nre, const float* nim,
                                        const int* labels, const float* emb,
                                        bf16* A, int idx) {
    if (idx >= BATCH * 224) return;
    int b = idx / 224, k = idx - b * 224;
    int p = k >= 112; int ci = k - p * 112;
    float v = 0.f;
    if (ci < CIN0) {
        if (!p) v = (ci < LAT) ? nre[b * LAT + ci] : emb[labels[b] * NCLS + (ci - LAT)];
        else    v = (ci < LAT) ? nim[b * LAT + ci] : 0.f;
    }
    A[idx] = f2b(v);
}

__global__ void prep_combined(const float* __restrict__ w1r, const float* __restrict__ w1i,
                              const float* __restrict__ w2r, const float* __restrict__ w2i,
                              const float* __restrict__ w3r, const float* __restrict__ w3i,
                              const float* __restrict__ w4r, const float* __restrict__ w4i,
                              const float* __restrict__ nre, const float* __restrict__ nim,
                              const int* __restrict__ labels, const float* __restrict__ emb,
                              bf16* __restrict__ B1, bf16* __restrict__ W2all,
                              bf16* __restrict__ W3all, bf16* __restrict__ W4all,
                              bf16* __restrict__ x0bf, float* __restrict__ Szero,
                              float* __restrict__ Zb) {
    int bid = blockIdx.x;
    if (bid < NB_W1) {
        w1prep_body(w1r, w1i, B1, bid * 256 + threadIdx.x);
    } else if (bid < NB_W1 + NB_W2) {
        wprep_panel_body<C1, C2>(w2r, w2i, W2all, (size_t)(bid - NB_W1) * 256 + threadIdx.x);
    } else if (bid < NB_W1 + NB_W2 + NB_W3) {
        wprep3_swz(w3r, w3i, W3all, (bid - NB_W1 - NB_W2) * 256 + threadIdx.x);
    } else if (bid < NB_W1 + NB_W2 + NB_W3 + NB_W4) {
        wprep4_body(w4r, w4i, W4all, (bid - NB_W1 - NB_W2 - NB_W3) * 256 + threadIdx.x);
    } else if (bid < NB_W1 + NB_W2 + NB_W3 + NB_W4 + NB_X0) {
        x0_body(nre, nim, labels, emb, x0bf,
                (bid - NB_W1 - NB_W2 - NB_W3 - NB_W4) * 256 + threadIdx.x);
    } else {
        int idx = (bid - NB_W1 - NB_W2 - NB_W3 - NB_W4 - NB_X0) * 256 + threadIdx.x;
        if (idx < 35840) Szero[idx] = 0.f;          // stat copies (143360 B)
        else if (idx < 36096) Zb[idx - 35840] = 0.f; // 1KB zero-page
    }
}

// ------- epilogue-stats: lq-shfl pre-reduce -> LDS -> atomics into sharded copy -------
__device__ __forceinline__ void epi_stats_flush(float* red, float* Scopy, int Cn,
                                                int cBaseGlobal, int tid, int lq,
                                                const int* clArr, float* s1,
                                                float* s2, float* sp, int isRe) {
    for (int i = tid; i < 320; i += 256) red[i] = 0.f;
    __syncthreads();
#pragma unroll
    for (int sn = 0; sn < 4; ++sn) {
        s1[sn] += __shfl_xor(s1[sn], 16, 64); s1[sn] += __shfl_xor(s1[sn], 32, 64);
        s2[sn] += __shfl_xor(s2[sn], 16, 64); s2[sn] += __shfl_xor(s2[sn], 32, 64);
        sp[sn] += __shfl_xor(sp[sn], 16, 64); sp[sn] += __shfl_xor(sp[sn], 32, 64);
    }
    if (lq == 0) {
#pragma unroll
        for (int sn = 0; sn < 4; ++sn) {
            int cl = clArr[sn];
            if (isRe) {
                atomicAdd(&red[cl * 5 + 0], s1[sn]);
                atomicAdd(&red[cl * 5 + 2], s2[sn]);
                atomicAdd(&red[cl * 5 + 4], sp[sn]);
            } else {
                atomicAdd(&red[cl * 5 + 1], s1[sn]);
                atomicAdd(&red[cl * 5 + 3], s2[sn]);
            }
        }
    }
    __syncthreads();
    for (int i = tid; i < 320; i += 256) {
        int cl = i / 5, st = i - cl * 5;
        atomicAdd(&Scopy[st * Cn + cBaseGlobal + cl], red[i]);
    }
}

// ---------------- gemm1 -> x1cl (interleaved), + BN1 stats ----------------
__global__ __launch_bounds__(256, 1) void gemm1(
    const bf16* __restrict__ A, const bf16* __restrict__ B,
    const float* __restrict__ b1r, const float* __restrict__ b1i,
    bf16* __restrict__ Y, float* __restrict__ Sstat) {
    __shared__ short As[128][40];
    __shared__ short Bs[128][40];
    const int tid = threadIdx.x;
    const int mBase = blockIdx.x * 128, nBase = blockIdx.y * 128;
    const int wid = tid >> 6, lane = tid & 63;
    const int wm = (wid >> 1) * 64, wn = (wid & 1) * 64;
    const int lm = lane & 15, lq = lane >> 4;

    f32x4 acc[4][4] = {};

    for (int k0 = 0; k0 < 224; k0 += 32) {
#pragma unroll
        for (int it = 0; it < 2; ++it) {
            int slot = tid + it * 256;
            int row = slot >> 2, kc = (slot & 3) * 8;
            int k = k0 + kc;
            *(uint4*)(&As[row][kc]) = *(const uint4*)(A + (size_t)(mBase + row) * 224 + k);
            *(uint4*)(&Bs[row][kc]) = *(const uint4*)(B + (size_t)(nBase + row) * 224 + k);
        }
        __syncthreads();
        bf16x8 af[4], bfr[4];
#pragma unroll
        for (int s = 0; s < 4; ++s) {
            af[s]  = *(const bf16x8*)(&As[wm + s * 16 + lm][lq * 8]);
            bfr[s] = *(const bf16x8*)(&Bs[wn + s * 16 + lm][lq * 8]);
        }
#pragma unroll
        for (int sm = 0; sm < 4; ++sm)
#pragma unroll
            for (int sn = 0; sn < 4; ++sn)
                acc[sm][sn] = __builtin_amdgcn_mfma_f32_16x16x32_bf16(af[sm], bfr[sn], acc[sm][sn], 0, 0, 0);
        __syncthreads();
    }

    float s1[4] = {}, s2[4] = {}, sp[4] = {};
    int clArr[4];
#pragma unroll
    for (int sn = 0; sn < 4; ++sn) clArr[sn] = (wn + sn * 16 + lm) >> 1;
    const int part = lm & 1;

#pragma unroll
    for (int sm = 0; sm < 4; ++sm) {
#pragma unroll
        for (int v = 0; v < 4; ++v) {
            int m = mBase + wm + sm * 16 + lq * 4 + v;
#pragma unroll
            for (int sn = 0; sn < 4; ++sn) {
                int n = nBase + wn + sn * 16 + lm;
                int c = (n & 1023) >> 1;
                float bias = part ? b1i[c] : b1r[c];
                float val = acc[sm][sn][v] + bias;
                float pv = __shfl_xor(val, 1, 64);
                s1[sn] += val; s2[sn] += val * val;
                if (!part) sp[sn] += val * pv;
                Y[(size_t)m * 16384 + n] = f2b(val);
            }
        }
    }
    int copy = (blockIdx.y * gridDim.x + blockIdx.x) & (NCOPY - 1);
    epi_stats_flush((float*)As, Sstat + (size_t)copy * 5 * C1, C1,
                    (nBase & 1023) >> 1, tid, lq, clArr, s1, s2, sp, !part);
}

// ------- BN apply+ReLU: block-cooperative fold of NCOPY stat copies -> LDS coefs -------
__global__ void bn_apply_v3(bf16* __restrict__ Y, const float* __restrict__ Scopies,
                            const float* __restrict__ grr, const float* __restrict__ gri,
                            const float* __restrict__ gii,
                            const float* __restrict__ betar, const float* __restrict__ betai,
                            int C, int total8, float invN) {
    __shared__ float coefs[6][512];
    for (int c = threadIdx.x; c < C; c += 256) {
        float sr = 0, si = 0, srr = 0, sii = 0, sri = 0;
        for (int cp = 0; cp < NCOPY; ++cp) {
            const float* S = Scopies + (size_t)cp * 5 * C;
            sr += S[c]; si += S[C + c]; srr += S[2 * C + c]; sii += S[3 * C + c]; sri += S[4 * C + c];
        }
        float mr = sr * invN, mi = si * invN;
        float crr = srr * invN - mr * mr + EPS;
        float cii = sii * invN - mi * mi + EPS;
        float cri = sri * invN - mr * mi;
        float s = sqrtf(crr * cii - cri * cri);
        float t = sqrtf(crr + cii + 2.f * s);
        float inv = 1.f / (s * t);
        float rrr = (cii + s) * inv, rii = (crr + s) * inv, rri = -cri * inv;
        float Grr = grr[c], Gri = gri[c], Gii = gii[c];
        float arr = Grr * rrr + Gri * rri, ari = Grr * rri + Gri * rii;
        float air = Gri * rrr + Gii * rri, aii = Gri * rri + Gii * rii;
        coefs[0][c] = arr; coefs[1][c] = ari;
        coefs[2][c] = betar[c] - arr * mr - ari * mi;
        coefs[3][c] = air; coefs[4][c] = aii;
        coefs[5][c] = betai[c] - air * mr - aii * mi;
    }
    __syncthreads();
    int idx = blockIdx.x * 256 + threadIdx.x;
    if (idx >= total8) return;
    size_t base = (size_t)idx * 8;
    int c0 = ((int)(base & (size_t)(2 * C - 1))) >> 1;
    bf16x8 v8 = *(const bf16x8*)(Y + base);
    bf16x8 o8;
#pragma unroll
    for (int u = 0; u < 4; ++u) {
        int c = c0 + u;
        float vr = s2f(v8[2 * u]), vi = s2f(v8[2 * u + 1]);
        o8[2 * u]     = f2s(fmaxf(coefs[0][c] * vr + coefs[1][c] * vi + coefs[2][c], 0.f));
        o8[2 * u + 1] = f2s(fmaxf(coefs[3][c] * vr + coefs[4][c] * vi + coefs[5][c], 0.f));
    }
    *(bf16x8*)(Y + base) = o8;
}

// ---------------- L2: MFMA GEMM 128x128, BK=64 (R2 structure, unchanged) ----------------
template<int CIN, int S, int N>
__global__ __launch_bounds__(256, 3) void gemm_convt_bd(
    const bf16* __restrict__ X, const bf16* __restrict__ Wall,
    const float* __restrict__ biasr, const float* __restrict__ biasi,
    bf16* __restrict__ Y, float* __restrict__ Sstat) {
    constexpr int TWOK = 8 * CIN, C2I = 2 * CIN, C2O = 2 * N, HOUT = 2 * S;
    constexpr int NSTEP = TWOK / 64;
    constexpr int CPS32 = C2I / 32;
    constexpr int LOG_CPS = (CIN == 512) ? 5 : 4;
    constexpr int GX = (BATCH * S * S) / 128;
    constexpr int GY = C2O / 128;
    constexpr int GZ = 4;
    constexpr int NWG = GX * GY * GZ;
    constexpr int CHUNK = NWG / 8;
    constexpr int NYZ = GY * GZ;
    __shared__ short As[2][2][128][40];

    const int phys = (blockIdx.z * GY + blockIdx.y) * GX + blockIdx.x;
    const int L = (phys & 7) * CHUNK + (phys >> 3);
    const int bx = L / NYZ;
    const int ryz = L - bx * NYZ;
    const int by = ryz % GY;
    const int bz = ryz / GY;

    const int cls = bz;
    const int py = cls >> 1, px = cls & 1;
    const int tid = threadIdx.x;
    const int mBase = bx * 128, nBase = by * 128;
    const int wid = tid >> 6, lane = tid & 63;
    const int wm = (wid >> 1) * 64, wn = (wid & 1) * 64;
    const int lm = lane & 15, lq = lane >> 4;
    const int dh0 = py ? 1 : 0, dh1 = py ? 0 : -1;
    const int dw0 = px ? 1 : 0, dw1 = px ? 0 : -1;

    const bf16* Wp = Wall
        + ((size_t)(cls * (C2O / 128) + by) * (TWOK / 32)) * 4096
        + ((wn >> 6) * 4) * 512 + lane * 8;

    int rowA[2], kcA[2];
    int offT[2][4];
#pragma unroll
    for (int j = 0; j < 2; ++j) {
        int slot = tid + j * 256;
        rowA[j] = slot >> 2; kcA[j] = (slot & 3) * 8;
        int m = mBase + rowA[j];
        int b = m / (S * S); int rem = m - b * (S * S);
        int i = rem / S, jj = rem % S;
#pragma unroll
        for (int t = 0; t < 4; ++t) {
            int a = t >> 1, e = t & 1;
            int ih = i + (a ? dh1 : dh0);
            int iw = jj + (e ? dw1 : dw0);
            offT[j][t] = ((unsigned)ih < (unsigned)S && (unsigned)iw < (unsigned)S)
                ? ((b * S + ih) * S + iw) * C2I : -1;
        }
    }

    auto loadA = [&](int ksn, uint4* av) {
        int kb0 = 2 * ksn;
        int t = kb0 >> LOG_CPS;
        int q0 = (kb0 & (CPS32 - 1)) << 5;
#pragma unroll
        for (int it = 0; it < 4; ++it) {
            int j = it & 1, h = it >> 1;
            int o = offT[j][t];
            uint4 v = {0u, 0u, 0u, 0u};
            if (o >= 0)
                v = *(const uint4*)(X + (size_t)o + q0 + h * 32 + kcA[j]);
            av[it] = v;
        }
    };

    f32x4 acc[4][4] = {};
    bf16x8 bA[4];

    {
        uint4 a0[4];
        loadA(0, a0);
#pragma unroll
        for (int sn = 0; sn < 4; ++sn) bA[sn] = *(const bf16x8*)(Wp + sn * 512);
#pragma unroll
        for (int it = 0; it < 4; ++it)
            *(uint4*)(&As[0][it >> 1][rowA[it & 1]][kcA[it & 1]]) = a0[it];
    }
    __syncthreads();

    for (int ks = 0; ks < NSTEP; ++ks) {
        const int cur = ks & 1;
        const bool hasNext = (ks + 1 < NSTEP);
        uint4 aS[4];
        if (hasNext) loadA(ks + 1, aS);
        bf16x8 bB[4];
        {
            const bf16* W1 = Wp + (size_t)(2 * ks + 1) * 4096;
#pragma unroll
            for (int sn = 0; sn < 4; ++sn) bB[sn] = *(const bf16x8*)(W1 + sn * 512);
        }
        {
            bf16x8 af[4];
#pragma unroll
            for (int s = 0; s < 4; ++s)
                af[s] = *(const bf16x8*)(&As[cur][0][wm + s * 16 + lm][lq * 8]);
#pragma unroll
            for (int sm = 0; sm < 4; ++sm)
#pragma unroll
                for (int sn = 0; sn < 4; ++sn)
                    acc[sm][sn] = __builtin_amdgcn_mfma_f32_16x16x32_bf16(af[sm], bA[sn], acc[sm][sn], 0, 0, 0);
        }
        if (hasNext) {
            const bf16* W2 = Wp + (size_t)(2 * ks + 2) * 4096;
#pragma unroll
            for (int sn = 0; sn < 4; ++sn) bA[sn] = *(const bf16x8*)(W2 + sn * 512);
        }
        {
            bf16x8 af[4];
#pragma unroll
            for (int s = 0; s < 4; ++s)
                af[s] = *(const bf16x8*)(&As[cur][1][wm + s * 16 + lm][lq * 8]);
#pragma unroll
            for (int sm = 0; sm < 4; ++sm)
#pragma unroll
                for (int sn = 0; sn < 4; ++sn)
                    acc[sm][sn] = __builtin_amdgcn_mfma_f32_16x16x32_bf16(af[sm], bB[sn], acc[sm][sn], 0, 0, 0);
        }
        if (hasNext) {
#pragma unroll
            for (int it = 0; it < 4; ++it)
                *(uint4*)(&As[1 - cur][it >> 1][rowA[it & 1]][kcA[it & 1]]) = aS[it];
        }
        __syncthreads();
    }

    float s1[4] = {}, s2[4] = {}, sp[4] = {};
    int clArr[4];
#pragma unroll
    for (int sn = 0; sn < 4; ++sn) clArr[sn] = (wn + sn * 16 + lm) >> 1;
    const int part = lm & 1;

#pragma unroll
    for (int sm = 0; sm < 4; ++sm) {
#pragma unroll
        for (int v = 0; v < 4; ++v) {
            int m = mBase + wm + sm * 16 + lq * 4 + v;
            int b = m / (S * S); int rem = m - b * (S * S);
            int i = rem / S, j = rem % S;
            int oh = 2 * i + py, ow = 2 * j + px;
            size_t rowoff = (size_t)((b * HOUT + oh) * HOUT + ow) * C2O;
#pragma unroll
            for (int sn = 0; sn < 4; ++sn) {
                int n = nBase + wn + sn * 16 + lm;
                int c = n >> 1;
                float bias = part ? biasi[c] : biasr[c];
                float val = acc[sm][sn][v] + bias;
                float pv = __shfl_xor(val, 1, 64);
                s1[sn] += val; s2[sn] += val * val;
                if (!part) sp[sn] += val * pv;
                Y[rowoff + n] = f2b(val);
            }
        }
    }
    int copy = L & (NCOPY - 1);
    epi_stats_flush((float*)As, Sstat + (size_t)copy * 5 * N, N,
                    nBase >> 1, tid, lq, clArr, s1, s2, sp, !part);
}

// ---------------- L3: 256x256 8-wave counted-vmcnt template, LDS-bounce epilogue ----------------
// R8: R7's "#pragma unroll 1" epilogue runtime-indexed acc[sm] -> whole accumulator
// allocated in scratch (rule #20): WRITE 35->296MB, dur 126us. Fix: K-loop unchanged;
// epilogue = LDS-bounce. Pass 1 (fully static unroll): val=acc+bias -> stats -> bf16 ->
// LDS[256][256] (=128KB, reuses staging bufs after final sync). No global addresses live.
// Pass 2: cooperative stream LDS->Y, 16B/lane chunks of 512B rows (conflict-free ds_read,
// coalesced global writes); runtime indexing touches only LDS, never acc.
#define DSRD_A(PAR, MH, KS, AF) do {                                                    \
    _Pragma("unroll")                                                                   \
    for (int s = 0; s < 4; ++s)                                                         \
        AF[s] = *(const bf16x8*)(LDSm + (PAR) * 16384 + (KS) * 8192                     \
                                 + (wm + (MH) * 64 + s * 16 + lm) * 32 + ardq);         \
} while (0)
#define DSRD_B(PAR, KS, BV) do {                                                        \
    _Pragma("unroll")                                                                   \
    for (int sn = 0; sn < 4; ++sn)                                                      \
        BV[sn] = *(const bf16x8*)(LDSm + 32768 + (PAR) * 16384 + (KS) * 8192            \
                                  + (wn + sn * 16 + lm) * 32 + ardq);                   \
} while (0)
#define MFMA16(MH, AF, BV) do {                                                         \
    __builtin_amdgcn_s_setprio(1);                                                      \
    _Pragma("unroll")                                                                   \
    for (int s = 0; s < 4; ++s)                                                         \
        _Pragma("unroll")                                                               \
        for (int sn = 0; sn < 4; ++sn)                                                  \
            acc[(MH) * 4 + s][sn] = __builtin_amdgcn_mfma_f32_16x16x32_bf16(            \
                AF[s], BV[sn], acc[(MH) * 4 + s][sn], 0, 0, 0);                         \
    __builtin_amdgcn_s_setprio(0);                                                      \
} while (0)
#define MEMFENCE asm volatile("" ::: "memory")

__global__ __launch_bounds__(512, 2) void gemm3_8ph(
    const bf16* __restrict__ X, const bf16* __restrict__ Wall,
    const float* __restrict__ biasr, const float* __restrict__ biasi,
    bf16* __restrict__ Y, float* __restrict__ Sstat,
    const bf16* __restrict__ zb) {
    constexpr int C2I = 512, C2O = 256;
    __shared__ short LDSm[65536];          // 128KB: A bytes [0,65536), B bytes [65536,131072)
    char* ldsB = (char*)LDSm;

    const int tid = threadIdx.x;
    const int phys = blockIdx.x;
    const int L = (phys & 7) * 32 + (phys >> 3);   // XCD swizzle: 8 bx-panels x 4 cls per XCD
    const int bx = L >> 2, cls = L & 3;
    const int py = cls >> 1, px = cls & 1;
    const int mBase = bx * 256;
    const int wid = tid >> 6, lane = tid & 63;
    const int wm = (wid >> 2) * 128;       // 2 M-waves (128 rows each)
    const int wn = (wid & 3) * 64;         // 4 N-waves
    const int lm = lane & 15, lq = lane >> 4;
    const int dh0 = py ? 1 : 0, dh1 = py ? 0 : -1;
    const int dw0 = px ? 1 : 0, dw1 = px ? 0 : -1;

    const bf16* Wsrc = Wall + (size_t)cls * 524288 + tid * 8;
    const int zoff = (int)(zb - X);

    // A staging: issue p covers rows p*128 + tid/4 (4 threads x 16B per 64B row-half).
    const int cgA = ((tid & 3) ^ ((tid >> 3) & 3)) * 8;   // inverse-swizzled source chunk
    int bP[2], iP[2], jP[2];
#pragma unroll
    for (int p = 0; p < 2; ++p) {
        int m = mBase + p * 128 + (tid >> 2);
        bP[p] = m >> 6; int rem = m & 63; iP[p] = rem >> 3; jP[p] = rem & 7;
    }
    // ds_read physical chunk: lq ^ ((row>>1)&3), row&15==lm for all fragments.
    const int ardq = (lq ^ ((lm >> 1) & 3)) * 8;

    f32x4 acc[8][4] = {};

    auto eoCalc = [&](int tp, int* eo) {
        int a = tp >> 1, e = tp & 1;
        int dh = a ? dh1 : dh0, dw = e ? dw1 : dw0;
#pragma unroll
        for (int p = 0; p < 2; ++p) {
            int ih = iP[p] + dh, iw = jP[p] + dw;
            eo[p] = ((unsigned)ih < 8u && (unsigned)iw < 8u)
                ? ((bP[p] * 8 + ih) * 8 + iw) * C2I : zoff;
        }
    };

    {   // prologue: stage kt=0 (par 0) in order {A-kh0 x2, B-kh0 x2, A-kh1 x2, B-kh1 x2}
        int eo0[2];
        eoCalc(0, eo0);
#pragma unroll
        for (int kh = 0; kh < 2; ++kh) {
#pragma unroll
            for (int p = 0; p < 2; ++p)
                gl_lds16(X + eo0[p] + kh * 32 + cgA,
                         ldsB + kh * 16384 + p * 8192 + tid * 16);
            MEMFENCE;
#pragma unroll
            for (int p = 0; p < 2; ++p)
                gl_lds16(Wsrc + (size_t)(kh * 2 + p) * 4096,
                         ldsB + 65536 + kh * 16384 + p * 8192 + tid * 16);
            MEMFENCE;
        }
        asm volatile("s_waitcnt vmcnt(4)" ::: "memory");
        __builtin_amdgcn_s_barrier();
    }

#pragma unroll 1
    for (int kt = 0; kt < 31; ++kt) {
        const int par = kt & 1;
        int eoN[2];
        eoCalc((kt + 1) >> 3, eoN);
        const int kcol = ((kt + 1) & 7) * 64;
        char* dstA = ldsB + (par ^ 1) * 32768;
        char* dstB = ldsB + 65536 + (par ^ 1) * 32768;
        bf16x8 af[4], bfv[4];
        // ph0: (mh0, ks0); stage A-kh0 of kt+1
        DSRD_A(par, 0, 0, af); DSRD_B(par, 0, bfv);
#pragma unroll
        for (int p = 0; p < 2; ++p)
            gl_lds16(X + eoN[p] + kcol + cgA, dstA + p * 8192 + tid * 16);
        MEMFENCE;
        __builtin_amdgcn_s_barrier();
        MFMA16(0, af, bfv);
        __builtin_amdgcn_s_barrier();
        MEMFENCE;
        // ph1: (mh1, ks0); stage B-kh0 of kt+1
        DSRD_A(par, 1, 0, af);
#pragma unroll
        for (int p = 0; p < 2; ++p)
            gl_lds16(Wsrc + (size_t)(((kt + 1) * 2 + 0) * 2 + p) * 4096,
                     dstB + p * 8192 + tid * 16);
        MEMFENCE;
        __builtin_amdgcn_s_barrier();
        MFMA16(1, af, bfv);
        asm volatile("s_waitcnt vmcnt(4)" ::: "memory");
        __builtin_amdgcn_s_barrier();
        MEMFENCE;
        // ph2: (mh0, ks1); stage A-kh1 of kt+1
        DSRD_A(par, 0, 1, af); DSRD_B(par, 1, bfv);
#pragma unroll
        for (int p = 0; p < 2; ++p)
            gl_lds16(X + eoN[p] + kcol + 32 + cgA, dstA + 16384 + p * 8192 + tid * 16);
        MEMFENCE;
        __builtin_amdgcn_s_barrier();
        MFMA16(0, af, bfv);
        __builtin_amdgcn_s_barrier();
        MEMFENCE;
        // ph3: (mh1, ks1); stage B-kh1 of kt+1
        DSRD_A(par, 1, 1, af);
#pragma unroll
        for (int p = 0; p < 2; ++p)
            gl_lds16(Wsrc + (size_t)(((kt + 1) * 2 + 1) * 2 + p) * 4096,
                     dstB + 16384 + p * 8192 + tid * 16);
        MEMFENCE;
        __builtin_amdgcn_s_barrier();
        MFMA16(1, af, bfv);
        asm volatile("s_waitcnt vmcnt(4)" ::: "memory");
        __builtin_amdgcn_s_barrier();
        MEMFENCE;
    }
    {   // peeled kt=31 (par=1): no staging; drain kh1's 4 in-flight loads before ph2 reads.
        bf16x8 af[4], bfv[4];
        DSRD_A(1, 0, 0, af); DSRD_B(1, 0, bfv);
        __builtin_amdgcn_s_barrier();
        MFMA16(0, af, bfv);
        __builtin_amdgcn_s_barrier();
        DSRD_A(1, 1, 0, af);
        __builtin_amdgcn_s_barrier();
        MFMA16(1, af, bfv);
        asm volatile("s_waitcnt vmcnt(0)" ::: "memory");
        __builtin_amdgcn_s_barrier();
        MEMFENCE;
        DSRD_A(1, 0, 1, af); DSRD_B(1, 1, bfv);
        __builtin_amdgcn_s_barrier();
        MFMA16(0, af, bfv);
        __builtin_amdgcn_s_barrier();
        DSRD_A(1, 1, 1, af);
        __builtin_amdgcn_s_barrier();
        MFMA16(1, af, bfv);
        __builtin_amdgcn_s_barrier();
    }

    __syncthreads();

    // ---- Pass 1: acc -> stats + bf16 tile in LDS (all indices static; ~zero addr regs) ----
    float s1[4] = {}, s2[4] = {}, sp[4] = {};
    int clArr[4];
#pragma unroll
    for (int sn = 0; sn < 4; ++sn) clArr[sn] = (wn + sn * 16 + lm) >> 1;
    const int part = lm & 1;
    float biasArr[4];
#pragma unroll
    for (int sn = 0; sn < 4; ++sn) {
        int c = (wn + sn * 16 + lm) >> 1;
        biasArr[sn] = part ? biasi[c] : biasr[c];
    }
#pragma unroll
    for (int sm = 0; sm < 8; ++sm) {
#pragma unroll
        for (int v = 0; v < 4; ++v) {
            int ml = wm + sm * 16 + lq * 4 + v;
#pragma unroll
            for (int sn = 0; sn < 4; ++sn) {
                int n = wn + sn * 16 + lm;
                float val = acc[sm][sn][v] + biasArr[sn];
                float pv = __shfl_xor(val, 1, 64);
                s1[sn] += val; s2[sn] += val * val;
                if (!part) sp[sn] += val * pv;
                LDSm[ml * 256 + n] = f2s(val);
            }
        }
    }
    __syncthreads();

    // ---- Pass 2: stream LDS tile -> Y (coalesced 512B rows, 16B/lane) ----
#pragma unroll 1
    for (int it = 0; it < 16; ++it) {
        int t = tid + it * 512;
        int ml = t >> 5, ch = t & 31;
        int m = mBase + ml;
        int b = m >> 6; int rem = m & 63;
        int i = rem >> 3, j = rem & 7;
        int oh = 2 * i + py, ow = 2 * j + px;
        size_t rowoff = (size_t)((b * 16 + oh) * 16 + ow) * C2O;
        *(uint4*)(Y + rowoff + ch * 8) = *(const uint4*)(LDSm + ml * 256 + ch * 8);
    }
    __syncthreads();

    // stats flush: 128 channels x 5 stats = 640 slots
    float* red = (float*)(&LDSm[0]);
    for (int i2 = tid; i2 < 640; i2 += 512) red[i2] = 0.f;
    __syncthreads();
#pragma unroll
    for (int sn = 0; sn < 4; ++sn) {
        s1[sn] += __shfl_xor(s1[sn], 16, 64); s1[sn] += __shfl_xor(s1[sn], 32, 64);
        s2[sn] += __shfl_xor(s2[sn], 16, 64); s2[sn] += __shfl_xor(s2[sn], 32, 64);
        sp[sn] += __shfl_xor(sp[sn], 16, 64); sp[sn] += __shfl_xor(sp[sn], 32, 64);
    }
    if (lq == 0) {
#pragma unroll
        for (int sn = 0; sn < 4; ++sn) {
            int cl = clArr[sn];
            if (!part) {
                atomicAdd(&red[cl * 5 + 0], s1[sn]);
                atomicAdd(&red[cl * 5 + 2], s2[sn]);
                atomicAdd(&red[cl * 5 + 4], sp[sn]);
            } else {
                atomicAdd(&red[cl * 5 + 1], s1[sn]);
                atomicAdd(&red[cl * 5 + 3], s2[sn]);
            }
        }
    }
    __syncthreads();
    float* Sc = Sstat + (size_t)(L & (NCOPY - 1)) * 5 * 128;
    for (int i2 = tid; i2 < 640; i2 += 512) {
        int cl = i2 / 5, st = i2 - cl * 5;
        atomicAdd(&Sc[st * 128 + cl], red[i2]);
    }
}

// ---------------- layer4 via MFMA, M-tile 256, LDS-staged ----------------
__global__ __launch_bounds__(256, 2) void conv4_mfma(
    const bf16* __restrict__ X, const bf16* __restrict__ Wall,
    const float* __restrict__ br, float* __restrict__ out) {
    constexpr int S = 16, TWOK = 1024, C2I = 256;
    constexpr int GX = 256, GZ = 4, NWG = GX * GZ, CHUNK = NWG / 8;
    __shared__ short As[256][40];
    __shared__ short Bs[16][40];

    const int phys = blockIdx.z * GX + blockIdx.x;
    const int L = (phys & 7) * CHUNK + (phys >> 3);
    const int bx = L >> 2;
    const int cls = L & 3;

    const int py = cls >> 1, px = cls & 1;
    const bf16* W = Wall + (size_t)cls * 16 * TWOK;
    const int tid = threadIdx.x;
    const int mBase = bx * 256;
    const int wid = tid >> 6, lane = tid & 63;
    const int wm = wid * 64;
    const int lm = lane & 15, lq = lane >> 4;
    const int dh0 = py ? 1 : 0, dh1 = py ? 0 : -1;
    const int dw0 = px ? 1 : 0, dw1 = px ? 0 : -1;

    int rowA[4], kcA[4];
    long offT[4][4];
#pragma unroll
    for (int it = 0; it < 4; ++it) {
        int slot = tid + it * 256;
        rowA[it] = slot >> 2; kcA[it] = (slot & 3) * 8;
        int m = mBase + rowA[it];
        int b = m >> 8; int rem = m & 255;
        int i = rem >> 4, j = rem & 15;
#pragma unroll
        for (int t = 0; t < 4; ++t) {
            int a = t >> 1, e = t & 1;
            int ih = i + (a ? dh1 : dh0);
            int iw = j + (e ? dw1 : dw0);
            offT[it][t] = ((unsigned)ih < (unsigned)S && (unsigned)iw < (unsigned)S)
                ? (long)((b * S + ih) * S + iw) * C2I : -1L;
        }
    }

    f32x4 acc[4] = {};

    for (int kb = 0; kb < TWOK / 32; ++kb) {
        int t = kb >> 3;
        int q0 = (kb & 7) << 5;
#pragma unroll
        for (int it = 0; it < 4; ++it) {
            long o = offT[it][t];
            uint4 v = {0u, 0u, 0u, 0u};
            if (o >= 0)
                v = *(const uint4*)(X + o + q0 + kcA[it]);
            *(uint4*)(&As[rowA[it]][kcA[it]]) = v;
        }
        if (tid < 64) {
            int row = tid >> 2, kc = (tid & 3) * 8;
            uint4 w = *(const uint4*)(W + (size_t)row * TWOK + kb * 32 + kc);
            *(uint4*)(&Bs[row][kc]) = w;
        }
        __syncthreads();
        bf16x8 bfr = *(const bf16x8*)(&Bs[lm][lq * 8]);
#pragma unroll
        for (int s = 0; s < 4; ++s) {
            bf16x8 af = *(const bf16x8*)(&As[wm + s * 16 + lm][lq * 8]);
            acc[s] = __builtin_amdgcn_mfma_f32_16x16x32_bf16(af, bfr, acc[s], 0, 0, 0);
        }
        __syncthreads();
    }

    int n = lm;
    if (n < NCH) {
        float bias = br[n];
#pragma unroll
        for (int s = 0; s < 4; ++s) {
#pragma unroll
            for (int v = 0; v < 4; ++v) {
                int m = mBase + wm + s * 16 + lq * 4 + v;
                int b = m >> 8; int rem = m & 255;
                int i = rem >> 4, j = rem & 15;
                int oh = 2 * i + py, ow = 2 * j + px;
                out[((size_t)(b * NCH + n) * 32 + oh) * 32 + ow] = tanhf(acc[s][v] + bias);
            }
        }
    }
}

extern "C" void kernel_launch(void* const* d_in, const int* in_sizes, int n_in,
                              void* d_out, int out_size, void* d_ws, size_t ws_size,
                              hipStream_t stream) {
    const float* noise_re = (const float*)d_in[0];
    const float* noise_im = (const float*)d_in[1];
    const int*   labels   = (const int*)d_in[2];
    const float* emb      = (const float*)d_in[3];
    const float* w1r = (const float*)d_in[4],  *w1i = (const float*)d_in[5];
    const float* b1r = (const float*)d_in[6],  *b1i = (const float*)d_in[7];
    const float* g1rr = (const float*)d_in[8], *g1ri = (const float*)d_in[9], *g1ii = (const float*)d_in[10];
    const float* n1br = (const float*)d_in[11], *n1bi = (const float*)d_in[12];
    const float* w2r = (const float*)d_in[13], *w2i = (const float*)d_in[14];
    const float* b2r = (const float*)d_in[15], *b2i = (const float*)d_in[16];
    const float* g2rr = (const float*)d_in[17], *g2ri = (const float*)d_in[18], *g2ii = (const float*)d_in[19];
    const float* n2br = (const float*)d_in[20], *n2bi = (const float*)d_in[21];
    const float* w3r = (const float*)d_in[22], *w3i = (const float*)d_in[23];
    const float* b3r = (const float*)d_in[24], *b3i = (const float*)d_in[25];
    const float* g3rr = (const float*)d_in[26], *g3ri = (const float*)d_in[27], *g3ii = (const float*)d_in[28];
    const float* n3br = (const float*)d_in[29], *n3bi = (const float*)d_in[30];
    const float* w4r = (const float*)d_in[31], *w4i = (const float*)d_in[32];
    const float* b4r = (const float*)d_in[33], *b4i = (const float*)d_in[34];

    // ---- workspace layout (bytes) ----
    char* ws = (char*)d_ws;
    bf16* y3cl = (bf16*)ws;
    bf16* x1cl = (bf16*)ws;
    bf16* B1    = (bf16*)(ws + 8388608);
    bf16* W2all = (bf16*)(ws + 15728640);
    bf16* y2cl  = (bf16*)(ws + 33554432);
    bf16* W3all = (bf16*)(ws + 50331648);
    bf16* x0bf  = (bf16*)(ws + 54547456);
    bf16* W4all = (bf16*)(ws + 54662144);
    float* S1 = (float*)(ws + 54793216);
    float* S2 = (float*)(ws + 54875136);
    float* S3 = (float*)(ws + 54916096);
    // 1KB zero-page in the unused gap between W3all end (54525952) and x0bf (54547456)
    float* Zb = (float*)(ws + 54526976);

    prep_combined<<<NB_W1 + NB_W2 + NB_W3 + NB_W4 + NB_X0 + NB_Z, 256, 0, stream>>>(
        w1r, w1i, w2r, w2i, w3r, w3i, w4r, w4i,
        noise_re, noise_im, labels, emb,
        B1, W2all, W3all, W4all, x0bf, S1, Zb);

    // L1 GEMM (+BN1 stats, sharded) -> x1cl
    gemm1<<<dim3(2, 128), 256, 0, stream>>>(x0bf, B1, b1r, b1i, x1cl, S1);
    bn_apply_v3<<<2048, 256, 0, stream>>>(x1cl, S1, g1rr, g1ri, g1ii, n1br, n1bi,
                                          C1, 524288, 1.f / 4096.f);

    // L2 GEMM (+BN2 stats) -> y2cl
    gemm_convt_bd<C1, 4, C2><<<dim3(32, 4, 4), 256, 0, stream>>>(x1cl, W2all, b2r, b2i, y2cl, S2);
    bn_apply_v3<<<4096, 256, 0, stream>>>(y2cl, S2, g2rr, g2ri, g2ii, n2br, n2bi,
                                          C2, 1048576, 1.f / 16384.f);

    // L3 GEMM (+BN3 stats) -> y3cl : 256x256 8-wave counted-vmcnt schedule (A+B via LDS)
    gemm3_8ph<<<dim3(256), 512, 0, stream>>>(y2cl, W3all, b3r, b3i, y3cl, S3,
                                             (const bf16*)Zb);
    bn_apply_v3<<<8192, 256, 0, stream>>>(y3cl, S3, g3rr, g3ri, g3ii, n3br, n3bi,
                                          C3, 2097152, 1.f / 65536.f);

    // L4: MFMA + tanh -> d_out (real part, fp32), M-tile 256
    conv4_mfma<<<dim3(256, 1, 4), 256, 0, stream>>>(y3cl, W4all, b4r, (float*)d_out);
}

// Round 10
// 450.219 us; speedup vs baseline: 1.1146x; 1.0151x over previous
//
#include <hip/hip_runtime.h>
#include <hip/hip_bf16.h>
#include <math.h>

#define BATCH 256
#define LAT 100
#define NCLS 10
#define CIN0 110
#define C1 512
#define C2 256
#define C3 128
#define NCH 3
#define EPS 1e-5f
#define NCOPY 8

typedef __hip_bfloat16 bf16;
typedef short bf16x8 __attribute__((ext_vector_type(8)));
typedef float f32x4 __attribute__((ext_vector_type(4)));

__device__ __forceinline__ float b2f(bf16 v) { return __bfloat162float(v); }
__device__ __forceinline__ bf16 f2b(float v) { return __float2bfloat16(v); }
__device__ __forceinline__ float s2f(short s) {
    unsigned u = ((unsigned)(unsigned short)s) << 16;
    return __builtin_bit_cast(float, u);
}
__device__ __forceinline__ short f2s(float f) {
    bf16 b = __float2bfloat16(f);
    return *(short*)&b;
}

__device__ __forceinline__ void gl_lds16(const void* g, void* l) {
    __builtin_amdgcn_global_load_lds(
        (__attribute__((address_space(1))) const void*)g,
        (__attribute__((address_space(3))) void*)l, 16, 0, 0);
}

// ======== INTERLEAVED complex channel layout everywhere ========
// R9 (resubmitted after GPU-acquisition timeout): all prep bodies vectorized 8x -- one
// bf16x8 store per thread. Index algebra: j = idx&7 maps to consecutive k within one
// (n, tap, parity-half) group because every boundary (224, 112, C2I, 512) is 8-aligned.
// 8 scattered reads collapse to 4 pairs. Grid 56057 -> 7113 blocks; output bitwise identical.
#define NB_W1 1792
#define NB_W2 4096
#define NB_W3 1024
#define NB_W4 32
#define NB_X0 28
#define NB_Z  141    // zero stat copies (35840 f) + 1KB zero-page for gload_lds OOB taps

__device__ __forceinline__ void w1prep_v8(const float* wr, const float* wi, bf16* B, int idx8) {
    if (idx8 >= 458752) return;          // 16384*224/8
    int idx = idx8 * 8;
    int n = idx / 224, k = idx - n * 224;
    int p = n >> 10;
    int c = (n & 1023) >> 1;
    int part = n & 1;
    int pk = k >= 112; int ci0 = k - pk * 112;
    size_t base = ((size_t)ci0 * C1 + c) * 16 + p;
    bf16x8 o;
#pragma unroll
    for (int j = 0; j < 8; ++j) {
        float v = 0.f;
        if (ci0 + j < CIN0) {
            float vr = wr[base + (size_t)j * (C1 * 16)];
            float vi = wi[base + (size_t)j * (C1 * 16)];
            v = (part == 0) ? (pk ? -vi : vr) : (pk ? vr : vi);
        }
        o[j] = f2s(v);
    }
    *(bf16x8*)(B + idx) = o;
}

template<int CIN, int N>
__device__ __forceinline__ void wprep_panel_v8(const float* wr, const float* wi, bf16* W,
                                               int idx8) {
    constexpr int TWOK = 8 * CIN, C2I = 2 * CIN;
    constexpr size_t per_cls = (size_t)2 * N * TWOK;
    size_t idx = (size_t)idx8 * 8;
    if (idx >= 4 * per_cls) return;
    int cls = (int)(idx / per_cls);
    size_t r = idx - (size_t)cls * per_cls;
    size_t chunk_nb = (size_t)TWOK * 128;
    int nb = (int)(r / chunk_nb);
    int r2 = (int)(r - (size_t)nb * chunk_nb);
    int kb = r2 >> 12;
    int w = r2 & 4095;
    int f = w >> 9;
    int l = (w >> 3) & 63;
    // j = w&7 == 0 (idx 8-aligned); k spans k0..k0+7 within one tap (q0+7 <= C2I-1).
    int n_virt = nb * 128 + (f >> 2) * 64 + (f & 3) * 16 + (l & 15);
    int k0 = kb * 32 + (l >> 4) * 8;
    int c = n_virt >> 1, part = n_virt & 1;
    int t = k0 / C2I;
    int q0 = k0 & (C2I - 1);             // even (k0 8-aligned)
    int ci0 = q0 >> 1;
    int py = cls >> 1, px = cls & 1;
    int a = t >> 1, e = t & 1;
    int kh = py ? (a ? 2 : 0) : (a ? 3 : 1);
    int kw = px ? (e ? 2 : 0) : (e ? 3 : 1);
    size_t wbase = ((size_t)ci0 * N + c) * 16 + kh * 4 + kw;
    bf16x8 o;
#pragma unroll
    for (int u = 0; u < 4; ++u) {
        float vr = wr[wbase + (size_t)u * (N * 16)];
        float vi = wi[wbase + (size_t)u * (N * 16)];
        o[2 * u]     = f2s((part == 0) ? vr : vi);    // p=0
        o[2 * u + 1] = f2s((part == 0) ? -vi : vr);   // p=1
    }
    *(bf16x8*)(W + idx) = o;
}

// W3S: pre-swizzled staging layout for gemm3_8ph's B tiles (R6-verified swizzle).
__device__ __forceinline__ void wprep3_swz_v8(const float* wr, const float* wi, bf16* W,
                                              int idx8) {
    int idx = idx8 * 8;
    if (idx >= 2097152) return;
    int cls = idx >> 19;
    int r = idx & 524287;
    int e16 = r >> 3;                    // j = r&7 == 0
    int tid = e16 & 511;
    int p = (e16 >> 9) & 1;
    int khh = (e16 >> 10) & 1;
    int kt = (e16 >> 11) & 31;
    int n = p * 128 + (tid >> 2);
    int clog = (tid & 3) ^ ((tid >> 3) & 3);
    int k0 = kt * 64 + khh * 32 + clog * 8;
    int c = n >> 1, part = n & 1;
    int t = k0 >> 9, q0 = k0 & 511;      // q0 even
    int ci0 = q0 >> 1;
    int py = cls >> 1, px = cls & 1;
    int a = t >> 1, e = t & 1;
    int kh_ = py ? (a ? 2 : 0) : (a ? 3 : 1);
    int kw_ = px ? (e ? 2 : 0) : (e ? 3 : 1);
    size_t wbase = ((size_t)ci0 * C3 + c) * 16 + kh_ * 4 + kw_;
    bf16x8 o;
#pragma unroll
    for (int u = 0; u < 4; ++u) {
        float vr = wr[wbase + (size_t)u * (C3 * 16)];
        float vi = wi[wbase + (size_t)u * (C3 * 16)];
        o[2 * u]     = f2s((part == 0) ? vr : vi);
        o[2 * u + 1] = f2s((part == 0) ? -vi : vr);
    }
    *(bf16x8*)(W + idx) = o;
}

__device__ __forceinline__ void wprep4_v8(const float* wr, const float* wi, bf16* W, int idx8) {
    if (idx8 >= 8192) return;
    int idx = idx8 * 8;
    int cls = idx >> 14, rem = idx & 16383;
    int py = cls >> 1, px = cls & 1;
    int n = rem >> 10, k0 = rem & 1023;
    bf16x8 o;
    if (n < NCH) {
        int t = k0 >> 8, q0 = k0 & 255;  // q0 even
        int ci0 = q0 >> 1;
        int a = t >> 1, e = t & 1;
        int kh = py ? (a ? 2 : 0) : (a ? 3 : 1);
        int kw = px ? (e ? 2 : 0) : (e ? 3 : 1);
        size_t wbase = ((size_t)ci0 * NCH + n) * 16 + kh * 4 + kw;
#pragma unroll
        for (int u = 0; u < 4; ++u) {
            float vr = wr[wbase + (size_t)u * (NCH * 16)];
            float vi = wi[wbase + (size_t)u * (NCH * 16)];
            o[2 * u]     = f2s(vr);          // p=0: wr
            o[2 * u + 1] = f2s(-vi);         // p=1: -wi
        }
    } else {
#pragma unroll
        for (int j = 0; j < 8; ++j) o[j] = f2s(0.f);
    }
    *(bf16x8*)(W + idx) = o;
}

__device__ __forceinline__ void x0_v8(const float* nre, const float* nim,
                                      const int* labels, const float* emb,
                                      bf16* A, int idx8) {
    if (idx8 >= 7168) return;            // 256*224/8
    int idx = idx8 * 8;
    int b = idx / 224, k = idx - b * 224;
    int p = k >= 112; int ci0 = k - p * 112;
    bf16x8 o;
#pragma unroll
    for (int j = 0; j < 8; ++j) {
        int ci = ci0 + j;
        float v = 0.f;
        if (ci < CIN0) {
            if (!p) v = (ci < LAT) ? nre[b * LAT + ci] : emb[labels[b] * NCLS + (ci - LAT)];
            else    v = (ci < LAT) ? nim[b * LAT + ci] : 0.f;
        }
        o[j] = f2s(v);
    }
    *(bf16x8*)(A + idx) = o;
}

__global__ void prep_combined(const float* __restrict__ w1r, const float* __restrict__ w1i,
                              const float* __restrict__ w2r, const float* __restrict__ w2i,
                              const float* __restrict__ w3r, const float* __restrict__ w3i,
                              const float* __restrict__ w4r, const float* __restrict__ w4i,
                              const float* __restrict__ nre, const float* __restrict__ nim,
                              const int* __restrict__ labels, const float* __restrict__ emb,
                              bf16* __restrict__ B1, bf16* __restrict__ W2all,
                              bf16* __restrict__ W3all, bf16* __restrict__ W4all,
                              bf16* __restrict__ x0bf, float* __restrict__ Szero,
                              float* __restrict__ Zb) {
    int bid = blockIdx.x;
    if (bid < NB_W1) {
        w1prep_v8(w1r, w1i, B1, bid * 256 + threadIdx.x);
    } else if (bid < NB_W1 + NB_W2) {
        wprep_panel_v8<C1, C2>(w2r, w2i, W2all, (bid - NB_W1) * 256 + threadIdx.x);
    } else if (bid < NB_W1 + NB_W2 + NB_W3) {
        wprep3_swz_v8(w3r, w3i, W3all, (bid - NB_W1 - NB_W2) * 256 + threadIdx.x);
    } else if (bid < NB_W1 + NB_W2 + NB_W3 + NB_W4) {
        wprep4_v8(w4r, w4i, W4all, (bid - NB_W1 - NB_W2 - NB_W3) * 256 + threadIdx.x);
    } else if (bid < NB_W1 + NB_W2 + NB_W3 + NB_W4 + NB_X0) {
        x0_v8(nre, nim, labels, emb, x0bf,
              (bid - NB_W1 - NB_W2 - NB_W3 - NB_W4) * 256 + threadIdx.x);
    } else {
        int idx = (bid - NB_W1 - NB_W2 - NB_W3 - NB_W4 - NB_X0) * 256 + threadIdx.x;
        if (idx < 35840) Szero[idx] = 0.f;          // stat copies (143360 B)
        else if (idx < 36096) Zb[idx - 35840] = 0.f; // 1KB zero-page
    }
}

// ------- epilogue-stats: lq-shfl pre-reduce -> LDS -> atomics into sharded copy -------
__device__ __forceinline__ void epi_stats_flush(float* red, float* Scopy, int Cn,
                                                int cBaseGlobal, int tid, int lq,
                                                const int* clArr, float* s1,
                                                float* s2, float* sp, int isRe) {
    for (int i = tid; i < 320; i += 256) red[i] = 0.f;
    __syncthreads();
#pragma unroll
    for (int sn = 0; sn < 4; ++sn) {
        s1[sn] += __shfl_xor(s1[sn], 16, 64); s1[sn] += __shfl_xor(s1[sn], 32, 64);
        s2[sn] += __shfl_xor(s2[sn], 16, 64); s2[sn] += __shfl_xor(s2[sn], 32, 64);
        sp[sn] += __shfl_xor(sp[sn], 16, 64); sp[sn] += __shfl_xor(sp[sn], 32, 64);
    }
    if (lq == 0) {
#pragma unroll
        for (int sn = 0; sn < 4; ++sn) {
            int cl = clArr[sn];
            if (isRe) {
                atomicAdd(&red[cl * 5 + 0], s1[sn]);
                atomicAdd(&red[cl * 5 + 2], s2[sn]);
                atomicAdd(&red[cl * 5 + 4], sp[sn]);
            } else {
                atomicAdd(&red[cl * 5 + 1], s1[sn]);
                atomicAdd(&red[cl * 5 + 3], s2[sn]);
            }
        }
    }
    __syncthreads();
    for (int i = tid; i < 320; i += 256) {
        int cl = i / 5, st = i - cl * 5;
        atomicAdd(&Scopy[st * Cn + cBaseGlobal + cl], red[i]);
    }
}

// ---------------- gemm1 -> x1cl (interleaved), + BN1 stats ----------------
__global__ __launch_bounds__(256, 1) void gemm1(
    const bf16* __restrict__ A, const bf16* __restrict__ B,
    const float* __restrict__ b1r, const float* __restrict__ b1i,
    bf16* __restrict__ Y, float* __restrict__ Sstat) {
    __shared__ short As[128][40];
    __shared__ short Bs[128][40];
    const int tid = threadIdx.x;
    const int mBase = blockIdx.x * 128, nBase = blockIdx.y * 128;
    const int wid = tid >> 6, lane = tid & 63;
    const int wm = (wid >> 1) * 64, wn = (wid & 1) * 64;
    const int lm = lane & 15, lq = lane >> 4;

    f32x4 acc[4][4] = {};

    for (int k0 = 0; k0 < 224; k0 += 32) {
#pragma unroll
        for (int it = 0; it < 2; ++it) {
            int slot = tid + it * 256;
            int row = slot >> 2, kc = (slot & 3) * 8;
            int k = k0 + kc;
            *(uint4*)(&As[row][kc]) = *(const uint4*)(A + (size_t)(mBase + row) * 224 + k);
            *(uint4*)(&Bs[row][kc]) = *(const uint4*)(B + (size_t)(nBase + row) * 224 + k);
        }
        __syncthreads();
        bf16x8 af[4], bfr[4];
#pragma unroll
        for (int s = 0; s < 4; ++s) {
            af[s]  = *(const bf16x8*)(&As[wm + s * 16 + lm][lq * 8]);
            bfr[s] = *(const bf16x8*)(&Bs[wn + s * 16 + lm][lq * 8]);
        }
#pragma unroll
        for (int sm = 0; sm < 4; ++sm)
#pragma unroll
            for (int sn = 0; sn < 4; ++sn)
                acc[sm][sn] = __builtin_amdgcn_mfma_f32_16x16x32_bf16(af[sm], bfr[sn], acc[sm][sn], 0, 0, 0);
        __syncthreads();
    }

    float s1[4] = {}, s2[4] = {}, sp[4] = {};
    int clArr[4];
#pragma unroll
    for (int sn = 0; sn < 4; ++sn) clArr[sn] = (wn + sn * 16 + lm) >> 1;
    const int part = lm & 1;

#pragma unroll
    for (int sm = 0; sm < 4; ++sm) {
#pragma unroll
        for (int v = 0; v < 4; ++v) {
            int m = mBase + wm + sm * 16 + lq * 4 + v;
#pragma unroll
            for (int sn = 0; sn < 4; ++sn) {
                int n = nBase + wn + sn * 16 + lm;
                int c = (n & 1023) >> 1;
                float bias = part ? b1i[c] : b1r[c];
                float val = acc[sm][sn][v] + bias;
                float pv = __shfl_xor(val, 1, 64);
                s1[sn] += val; s2[sn] += val * val;
                if (!part) sp[sn] += val * pv;
                Y[(size_t)m * 16384 + n] = f2b(val);
            }
        }
    }
    int copy = (blockIdx.y * gridDim.x + blockIdx.x) & (NCOPY - 1);
    epi_stats_flush((float*)As, Sstat + (size_t)copy * 5 * C1, C1,
                    (nBase & 1023) >> 1, tid, lq, clArr, s1, s2, sp, !part);
}

// ------- BN apply+ReLU: block-cooperative fold of NCOPY stat copies -> LDS coefs -------
__global__ void bn_apply_v3(bf16* __restrict__ Y, const float* __restrict__ Scopies,
                            const float* __restrict__ grr, const float* __restrict__ gri,
                            const float* __restrict__ gii,
                            const float* __restrict__ betar, const float* __restrict__ betai,
                            int C, int total8, float invN) {
    __shared__ float coefs[6][512];
    for (int c = threadIdx.x; c < C; c += 256) {
        float sr = 0, si = 0, srr = 0, sii = 0, sri = 0;
        for (int cp = 0; cp < NCOPY; ++cp) {
            const float* S = Scopies + (size_t)cp * 5 * C;
            sr += S[c]; si += S[C + c]; srr += S[2 * C + c]; sii += S[3 * C + c]; sri += S[4 * C + c];
        }
        float mr = sr * invN, mi = si * invN;
        float crr = srr * invN - mr * mr + EPS;
        float cii = sii * invN - mi * mi + EPS;
        float cri = sri * invN - mr * mi;
        float s = sqrtf(crr * cii - cri * cri);
        float t = sqrtf(crr + cii + 2.f * s);
        float inv = 1.f / (s * t);
        float rrr = (cii + s) * inv, rii = (crr + s) * inv, rri = -cri * inv;
        float Grr = grr[c], Gri = gri[c], Gii = gii[c];
        float arr = Grr * rrr + Gri * rri, ari = Grr * rri + Gri * rii;
        float air = Gri * rrr + Gii * rri, aii = Gri * rri + Gii * rii;
        coefs[0][c] = arr; coefs[1][c] = ari;
        coefs[2][c] = betar[c] - arr * mr - ari * mi;
        coefs[3][c] = air; coefs[4][c] = aii;
        coefs[5][c] = betai[c] - air * mr - aii * mi;
    }
    __syncthreads();
    int idx = blockIdx.x * 256 + threadIdx.x;
    if (idx >= total8) return;
    size_t base = (size_t)idx * 8;
    int c0 = ((int)(base & (size_t)(2 * C - 1))) >> 1;
    bf16x8 v8 = *(const bf16x8*)(Y + base);
    bf16x8 o8;
#pragma unroll
    for (int u = 0; u < 4; ++u) {
        int c = c0 + u;
        float vr = s2f(v8[2 * u]), vi = s2f(v8[2 * u + 1]);
        o8[2 * u]     = f2s(fmaxf(coefs[0][c] * vr + coefs[1][c] * vi + coefs[2][c], 0.f));
        o8[2 * u + 1] = f2s(fmaxf(coefs[3][c] * vr + coefs[4][c] * vi + coefs[5][c], 0.f));
    }
    *(bf16x8*)(Y + base) = o8;
}

// ---------------- L2: MFMA GEMM 128x128, BK=64 (R2 structure, unchanged) ----------------
template<int CIN, int S, int N>
__global__ __launch_bounds__(256, 3) void gemm_convt_bd(
    const bf16* __restrict__ X, const bf16* __restrict__ Wall,
    const float* __restrict__ biasr, const float* __restrict__ biasi,
    bf16* __restrict__ Y, float* __restrict__ Sstat) {
    constexpr int TWOK = 8 * CIN, C2I = 2 * CIN, C2O = 2 * N, HOUT = 2 * S;
    constexpr int NSTEP = TWOK / 64;
    constexpr int CPS32 = C2I / 32;
    constexpr int LOG_CPS = (CIN == 512) ? 5 : 4;
    constexpr int GX = (BATCH * S * S) / 128;
    constexpr int GY = C2O / 128;
    constexpr int GZ = 4;
    constexpr int NWG = GX * GY * GZ;
    constexpr int CHUNK = NWG / 8;
    constexpr int NYZ = GY * GZ;
    __shared__ short As[2][2][128][40];

    const int phys = (blockIdx.z * GY + blockIdx.y) * GX + blockIdx.x;
    const int L = (phys & 7) * CHUNK + (phys >> 3);
    const int bx = L / NYZ;
    const int ryz = L - bx * NYZ;
    const int by = ryz % GY;
    const int bz = ryz / GY;

    const int cls = bz;
    const int py = cls >> 1, px = cls & 1;
    const int tid = threadIdx.x;
    const int mBase = bx * 128, nBase = by * 128;
    const int wid = tid >> 6, lane = tid & 63;
    const int wm = (wid >> 1) * 64, wn = (wid & 1) * 64;
    const int lm = lane & 15, lq = lane >> 4;
    const int dh0 = py ? 1 : 0, dh1 = py ? 0 : -1;
    const int dw0 = px ? 1 : 0, dw1 = px ? 0 : -1;

    const bf16* Wp = Wall
        + ((size_t)(cls * (C2O / 128) + by) * (TWOK / 32)) * 4096
        + ((wn >> 6) * 4) * 512 + lane * 8;

    int rowA[2], kcA[2];
    int offT[2][4];
#pragma unroll
    for (int j = 0; j < 2; ++j) {
        int slot = tid + j * 256;
        rowA[j] = slot >> 2; kcA[j] = (slot & 3) * 8;
        int m = mBase + rowA[j];
        int b = m / (S * S); int rem = m - b * (S * S);
        int i = rem / S, jj = rem % S;
#pragma unroll
        for (int t = 0; t < 4; ++t) {
            int a = t >> 1, e = t & 1;
            int ih = i + (a ? dh1 : dh0);
            int iw = jj + (e ? dw1 : dw0);
            offT[j][t] = ((unsigned)ih < (unsigned)S && (unsigned)iw < (unsigned)S)
                ? ((b * S + ih) * S + iw) * C2I : -1;
        }
    }

    auto loadA = [&](int ksn, uint4* av) {
        int kb0 = 2 * ksn;
        int t = kb0 >> LOG_CPS;
        int q0 = (kb0 & (CPS32 - 1)) << 5;
#pragma unroll
        for (int it = 0; it < 4; ++it) {
            int j = it & 1, h = it >> 1;
            int o = offT[j][t];
            uint4 v = {0u, 0u, 0u, 0u};
            if (o >= 0)
                v = *(const uint4*)(X + (size_t)o + q0 + h * 32 + kcA[j]);
            av[it] = v;
        }
    };

    f32x4 acc[4][4] = {};
    bf16x8 bA[4];

    {
        uint4 a0[4];
        loadA(0, a0);
#pragma unroll
        for (int sn = 0; sn < 4; ++sn) bA[sn] = *(const bf16x8*)(Wp + sn * 512);
#pragma unroll
        for (int it = 0; it < 4; ++it)
            *(uint4*)(&As[0][it >> 1][rowA[it & 1]][kcA[it & 1]]) = a0[it];
    }
    __syncthreads();

    for (int ks = 0; ks < NSTEP; ++ks) {
        const int cur = ks & 1;
        const bool hasNext = (ks + 1 < NSTEP);
        uint4 aS[4];
        if (hasNext) loadA(ks + 1, aS);
        bf16x8 bB[4];
        {
            const bf16* W1 = Wp + (size_t)(2 * ks + 1) * 4096;
#pragma unroll
            for (int sn = 0; sn < 4; ++sn) bB[sn] = *(const bf16x8*)(W1 + sn * 512);
        }
        {
            bf16x8 af[4];
#pragma unroll
            for (int s = 0; s < 4; ++s)
                af[s] = *(const bf16x8*)(&As[cur][0][wm + s * 16 + lm][lq * 8]);
#pragma unroll
            for (int sm = 0; sm < 4; ++sm)
#pragma unroll
                for (int sn = 0; sn < 4; ++sn)
                    acc[sm][sn] = __builtin_amdgcn_mfma_f32_16x16x32_bf16(af[sm], bA[sn], acc[sm][sn], 0, 0, 0);
        }
        if (hasNext) {
            const bf16* W2 = Wp + (size_t)(2 * ks + 2) * 4096;
#pragma unroll
            for (int sn = 0; sn < 4; ++sn) bA[sn] = *(const bf16x8*)(W2 + sn * 512);
        }
        {
            bf16x8 af[4];
#pragma unroll
            for (int s = 0; s < 4; ++s)
                af[s] = *(const bf16x8*)(&As[cur][1][wm + s * 16 + lm][lq * 8]);
#pragma unroll
            for (int sm = 0; sm < 4; ++sm)
#pragma unroll
                for (int sn = 0; sn < 4; ++sn)
                    acc[sm][sn] = __builtin_amdgcn_mfma_f32_16x16x32_bf16(af[sm], bB[sn], acc[sm][sn], 0, 0, 0);
        }
        if (hasNext) {
#pragma unroll
            for (int it = 0; it < 4; ++it)
                *(uint4*)(&As[1 - cur][it >> 1][rowA[it & 1]][kcA[it & 1]]) = aS[it];
        }
        __syncthreads();
    }

    float s1[4] = {}, s2[4] = {}, sp[4] = {};
    int clArr[4];
#pragma unroll
    for (int sn = 0; sn < 4; ++sn) clArr[sn] = (wn + sn * 16 + lm) >> 1;
    const int part = lm & 1;

#pragma unroll
    for (int sm = 0; sm < 4; ++sm) {
#pragma unroll
        for (int v = 0; v < 4; ++v) {
            int m = mBase + wm + sm * 16 + lq * 4 + v;
            int b = m / (S * S); int rem = m - b * (S * S);
            int i = rem / S, j = rem % S;
            int oh = 2 * i + py, ow = 2 * j + px;
            size_t rowoff = (size_t)((b * HOUT + oh) * HOUT + ow) * C2O;
#pragma unroll
            for (int sn = 0; sn < 4; ++sn) {
                int n = nBase + wn + sn * 16 + lm;
                int c = n >> 1;
                float bias = part ? biasi[c] : biasr[c];
                float val = acc[sm][sn][v] + bias;
                float pv = __shfl_xor(val, 1, 64);
                s1[sn] += val; s2[sn] += val * val;
                if (!part) sp[sn] += val * pv;
                Y[rowoff + n] = f2b(val);
            }
        }
    }
    int copy = L & (NCOPY - 1);
    epi_stats_flush((float*)As, Sstat + (size_t)copy * 5 * N, N,
                    nBase >> 1, tid, lq, clArr, s1, s2, sp, !part);
}

// ---------------- L3: 256x256 8-wave counted-vmcnt template, LDS-bounce epilogue ----------------
#define DSRD_A(PAR, MH, KS, AF) do {                                                    \
    _Pragma("unroll")                                                                   \
    for (int s = 0; s < 4; ++s)                                                         \
        AF[s] = *(const bf16x8*)(LDSm + (PAR) * 16384 + (KS) * 8192                     \
                                 + (wm + (MH) * 64 + s * 16 + lm) * 32 + ardq);         \
} while (0)
#define DSRD_B(PAR, KS, BV) do {                                                        \
    _Pragma("unroll")                                                                   \
    for (int sn = 0; sn < 4; ++sn)                                                      \
        BV[sn] = *(const bf16x8*)(LDSm + 32768 + (PAR) * 16384 + (KS) * 8192            \
                                  + (wn + sn * 16 + lm) * 32 + ardq);                   \
} while (0)
#define MFMA16(MH, AF, BV) do {                                                         \
    __builtin_amdgcn_s_setprio(1);                                                      \
    _Pragma("unroll")                                                                   \
    for (int s = 0; s < 4; ++s)                                                         \
        _Pragma("unroll")                                                               \
        for (int sn = 0; sn < 4; ++sn)                                                  \
            acc[(MH) * 4 + s][sn] = __builtin_amdgcn_mfma_f32_16x16x32_bf16(            \
                AF[s], BV[sn], acc[(MH) * 4 + s][sn], 0, 0, 0);                         \
    __builtin_amdgcn_s_setprio(0);                                                      \
} while (0)
#define MEMFENCE asm volatile("" ::: "memory")

__global__ __launch_bounds__(512, 2) void gemm3_8ph(
    const bf16* __restrict__ X, const bf16* __restrict__ Wall,
    const float* __restrict__ biasr, const float* __restrict__ biasi,
    bf16* __restrict__ Y, float* __restrict__ Sstat,
    const bf16* __restrict__ zb) {
    constexpr int C2I = 512, C2O = 256;
    __shared__ short LDSm[65536];          // 128KB: A bytes [0,65536), B bytes [65536,131072)
    char* ldsB = (char*)LDSm;

    const int tid = threadIdx.x;
    const int phys = blockIdx.x;
    const int L = (phys & 7) * 32 + (phys >> 3);   // XCD swizzle: 8 bx-panels x 4 cls per XCD
    const int bx = L >> 2, cls = L & 3;
    const int py = cls >> 1, px = cls & 1;
    const int mBase = bx * 256;
    const int wid = tid >> 6, lane = tid & 63;
    const int wm = (wid >> 2) * 128;       // 2 M-waves (128 rows each)
    const int wn = (wid & 3) * 64;         // 4 N-waves
    const int lm = lane & 15, lq = lane >> 4;
    const int dh0 = py ? 1 : 0, dh1 = py ? 0 : -1;
    const int dw0 = px ? 1 : 0, dw1 = px ? 0 : -1;

    const bf16* Wsrc = Wall + (size_t)cls * 524288 + tid * 8;
    const int zoff = (int)(zb - X);

    // A staging: issue p covers rows p*128 + tid/4 (4 threads x 16B per 64B row-half).
    const int cgA = ((tid & 3) ^ ((tid >> 3) & 3)) * 8;   // inverse-swizzled source chunk
    int bP[2], iP[2], jP[2];
#pragma unroll
    for (int p = 0; p < 2; ++p) {
        int m = mBase + p * 128 + (tid >> 2);
        bP[p] = m >> 6; int rem = m & 63; iP[p] = rem >> 3; jP[p] = rem & 7;
    }
    // ds_read physical chunk: lq ^ ((row>>1)&3), row&15==lm for all fragments.
    const int ardq = (lq ^ ((lm >> 1) & 3)) * 8;

    f32x4 acc[8][4] = {};

    auto eoCalc = [&](int tp, int* eo) {
        int a = tp >> 1, e = tp & 1;
        int dh = a ? dh1 : dh0, dw = e ? dw1 : dw0;
#pragma unroll
        for (int p = 0; p < 2; ++p) {
            int ih = iP[p] + dh, iw = jP[p] + dw;
            eo[p] = ((unsigned)ih < 8u && (unsigned)iw < 8u)
                ? ((bP[p] * 8 + ih) * 8 + iw) * C2I : zoff;
        }
    };

    {   // prologue: stage kt=0 (par 0) in order {A-kh0 x2, B-kh0 x2, A-kh1 x2, B-kh1 x2}
        int eo0[2];
        eoCalc(0, eo0);
#pragma unroll
        for (int kh = 0; kh < 2; ++kh) {
#pragma unroll
            for (int p = 0; p < 2; ++p)
                gl_lds16(X + eo0[p] + kh * 32 + cgA,
                         ldsB + kh * 16384 + p * 8192 + tid * 16);
            MEMFENCE;
#pragma unroll
            for (int p = 0; p < 2; ++p)
                gl_lds16(Wsrc + (size_t)(kh * 2 + p) * 4096,
                         ldsB + 65536 + kh * 16384 + p * 8192 + tid * 16);
            MEMFENCE;
        }
        asm volatile("s_waitcnt vmcnt(4)" ::: "memory");
        __builtin_amdgcn_s_barrier();
    }

#pragma unroll 1
    for (int kt = 0; kt < 31; ++kt) {
        const int par = kt & 1;
        int eoN[2];
        eoCalc((kt + 1) >> 3, eoN);
        const int kcol = ((kt + 1) & 7) * 64;
        char* dstA = ldsB + (par ^ 1) * 32768;
        char* dstB = ldsB + 65536 + (par ^ 1) * 32768;
        bf16x8 af[4], bfv[4];
        // ph0: (mh0, ks0); stage A-kh0 of kt+1
        DSRD_A(par, 0, 0, af); DSRD_B(par, 0, bfv);
#pragma unroll
        for (int p = 0; p < 2; ++p)
            gl_lds16(X + eoN[p] + kcol + cgA, dstA + p * 8192 + tid * 16);
        MEMFENCE;
        __builtin_amdgcn_s_barrier();
        MFMA16(0, af, bfv);
        __builtin_amdgcn_s_barrier();
        MEMFENCE;
        // ph1: (mh1, ks0); stage B-kh0 of kt+1
        DSRD_A(par, 1, 0, af);
#pragma unroll
        for (int p = 0; p < 2; ++p)
            gl_lds16(Wsrc + (size_t)(((kt + 1) * 2 + 0) * 2 + p) * 4096,
                     dstB + p * 8192 + tid * 16);
        MEMFENCE;
        __builtin_amdgcn_s_barrier();
        MFMA16(1, af, bfv);
        asm volatile("s_waitcnt vmcnt(4)" ::: "memory");
        __builtin_amdgcn_s_barrier();
        MEMFENCE;
        // ph2: (mh0, ks1); stage A-kh1 of kt+1
        DSRD_A(par, 0, 1, af); DSRD_B(par, 1, bfv);
#pragma unroll
        for (int p = 0; p < 2; ++p)
            gl_lds16(X + eoN[p] + kcol + 32 + cgA, dstA + 16384 + p * 8192 + tid * 16);
        MEMFENCE;
        __builtin_amdgcn_s_barrier();
        MFMA16(0, af, bfv);
        __builtin_amdgcn_s_barrier();
        MEMFENCE;
        // ph3: (mh1, ks1); stage B-kh1 of kt+1
        DSRD_A(par, 1, 1, af);
#pragma unroll
        for (int p = 0; p < 2; ++p)
            gl_lds16(Wsrc + (size_t)(((kt + 1) * 2 + 1) * 2 + p) * 4096,
                     dstB + 16384 + p * 8192 + tid * 16);
        MEMFENCE;
        __builtin_amdgcn_s_barrier();
        MFMA16(1, af, bfv);
        asm volatile("s_waitcnt vmcnt(4)" ::: "memory");
        __builtin_amdgcn_s_barrier();
        MEMFENCE;
    }
    {   // peeled kt=31 (par=1): no staging; drain kh1's 4 in-flight loads before ph2 reads.
        bf16x8 af[4], bfv[4];
        DSRD_A(1, 0, 0, af); DSRD_B(1, 0, bfv);
        __builtin_amdgcn_s_barrier();
        MFMA16(0, af, bfv);
        __builtin_amdgcn_s_barrier();
        DSRD_A(1, 1, 0, af);
        __builtin_amdgcn_s_barrier();
        MFMA16(1, af, bfv);
        asm volatile("s_waitcnt vmcnt(0)" ::: "memory");
        __builtin_amdgcn_s_barrier();
        MEMFENCE;
        DSRD_A(1, 0, 1, af); DSRD_B(1, 1, bfv);
        __builtin_amdgcn_s_barrier();
        MFMA16(0, af, bfv);
        __builtin_amdgcn_s_barrier();
        DSRD_A(1, 1, 1, af);
        __builtin_amdgcn_s_barrier();
        MFMA16(1, af, bfv);
        __builtin_amdgcn_s_barrier();
    }

    __syncthreads();

    // ---- Pass 1: acc -> stats + bf16 tile in LDS (all indices static; ~zero addr regs) ----
    float s1[4] = {}, s2[4] = {}, sp[4] = {};
    int clArr[4];
#pragma unroll
    for (int sn = 0; sn < 4; ++sn) clArr[sn] = (wn + sn * 16 + lm) >> 1;
    const int part = lm & 1;
    float biasArr[4];
#pragma unroll
    for (int sn = 0; sn < 4; ++sn) {
        int c = (wn + sn * 16 + lm) >> 1;
        biasArr[sn] = part ? biasi[c] : biasr[c];
    }
#pragma unroll
    for (int sm = 0; sm < 8; ++sm) {
#pragma unroll
        for (int v = 0; v < 4; ++v) {
            int ml = wm + sm * 16 + lq * 4 + v;
#pragma unroll
            for (int sn = 0; sn < 4; ++sn) {
                int n = wn + sn * 16 + lm;
                float val = acc[sm][sn][v] + biasArr[sn];
                float pv = __shfl_xor(val, 1, 64);
                s1[sn] += val; s2[sn] += val * val;
                if (!part) sp[sn] += val * pv;
                LDSm[ml * 256 + n] = f2s(val);
            }
        }
    }
    __syncthreads();

    // ---- Pass 2: stream LDS tile -> Y (coalesced 512B rows, 16B/lane) ----
#pragma unroll 1
    for (int it = 0; it < 16; ++it) {
        int t = tid + it * 512;
        int ml = t >> 5, ch = t & 31;
        int m = mBase + ml;
        int b = m >> 6; int rem = m & 63;
        int i = rem >> 3, j = rem & 7;
        int oh = 2 * i + py, ow = 2 * j + px;
        size_t rowoff = (size_t)((b * 16 + oh) * 16 + ow) * C2O;
        *(uint4*)(Y + rowoff + ch * 8) = *(const uint4*)(LDSm + ml * 256 + ch * 8);
    }
    __syncthreads();

    // stats flush: 128 channels x 5 stats = 640 slots
    float* red = (float*)(&LDSm[0]);
    for (int i2 = tid; i2 < 640; i2 += 512) red[i2] = 0.f;
    __syncthreads();
#pragma unroll
    for (int sn = 0; sn < 4; ++sn) {
        s1[sn] += __shfl_xor(s1[sn], 16, 64); s1[sn] += __shfl_xor(s1[sn], 32, 64);
        s2[sn] += __shfl_xor(s2[sn], 16, 64); s2[sn] += __shfl_xor(s2[sn], 32, 64);
        sp[sn] += __shfl_xor(sp[sn], 16, 64); sp[sn] += __shfl_xor(sp[sn], 32, 64);
    }
    if (lq == 0) {
#pragma unroll
        for (int sn = 0; sn < 4; ++sn) {
            int cl = clArr[sn];
            if (!part) {
                atomicAdd(&red[cl * 5 + 0], s1[sn]);
                atomicAdd(&red[cl * 5 + 2], s2[sn]);
                atomicAdd(&red[cl * 5 + 4], sp[sn]);
            } else {
                atomicAdd(&red[cl * 5 + 1], s1[sn]);
                atomicAdd(&red[cl * 5 + 3], s2[sn]);
            }
        }
    }
    __syncthreads();
    float* Sc = Sstat + (size_t)(L & (NCOPY - 1)) * 5 * 128;
    for (int i2 = tid; i2 < 640; i2 += 512) {
        int cl = i2 / 5, st = i2 - cl * 5;
        atomicAdd(&Sc[st * 128 + cl], red[i2]);
    }
}

// ---------------- layer4 via MFMA, M-tile 256, LDS-staged ----------------
__global__ __launch_bounds__(256, 2) void conv4_mfma(
    const bf16* __restrict__ X, const bf16* __restrict__ Wall,
    const float* __restrict__ br, float* __restrict__ out) {
    constexpr int S = 16, TWOK = 1024, C2I = 256;
    constexpr int GX = 256, GZ = 4, NWG = GX * GZ, CHUNK = NWG / 8;
    __shared__ short As[256][40];
    __shared__ short Bs[16][40];

    const int phys = blockIdx.z * GX + blockIdx.x;
    const int L = (phys & 7) * CHUNK + (phys >> 3);
    const int bx = L >> 2;
    const int cls = L & 3;

    const int py = cls >> 1, px = cls & 1;
    const bf16* W = Wall + (size_t)cls * 16 * TWOK;
    const int tid = threadIdx.x;
    const int mBase = bx * 256;
    const int wid = tid >> 6, lane = tid & 63;
    const int wm = wid * 64;
    const int lm = lane & 15, lq = lane >> 4;
    const int dh0 = py ? 1 : 0, dh1 = py ? 0 : -1;
    const int dw0 = px ? 1 : 0, dw1 = px ? 0 : -1;

    int rowA[4], kcA[4];
    long offT[4][4];
#pragma unroll
    for (int it = 0; it < 4; ++it) {
        int slot = tid + it * 256;
        rowA[it] = slot >> 2; kcA[it] = (slot & 3) * 8;
        int m = mBase + rowA[it];
        int b = m >> 8; int rem = m & 255;
        int i = rem >> 4, j = rem & 15;
#pragma unroll
        for (int t = 0; t < 4; ++t) {
            int a = t >> 1, e = t & 1;
            int ih = i + (a ? dh1 : dh0);
            int iw = j + (e ? dw1 : dw0);
            offT[it][t] = ((unsigned)ih < (unsigned)S && (unsigned)iw < (unsigned)S)
                ? (long)((b * S + ih) * S + iw) * C2I : -1L;
        }
    }

    f32x4 acc[4] = {};

    for (int kb = 0; kb < TWOK / 32; ++kb) {
        int t = kb >> 3;
        int q0 = (kb & 7) << 5;
#pragma unroll
        for (int it = 0; it < 4; ++it) {
            long o = offT[it][t];
            uint4 v = {0u, 0u, 0u, 0u};
            if (o >= 0)
                v = *(const uint4*)(X + o + q0 + kcA[it]);
            *(uint4*)(&As[rowA[it]][kcA[it]]) = v;
        }
        if (tid < 64) {
            int row = tid >> 2, kc = (tid & 3) * 8;
            uint4 w = *(const uint4*)(W + (size_t)row * TWOK + kb * 32 + kc);
            *(uint4*)(&Bs[row][kc]) = w;
        }
        __syncthreads();
        bf16x8 bfr = *(const bf16x8*)(&Bs[lm][lq * 8]);
#pragma unroll
        for (int s = 0; s < 4; ++s) {
            bf16x8 af = *(const bf16x8*)(&As[wm + s * 16 + lm][lq * 8]);
            acc[s] = __builtin_amdgcn_mfma_f32_16x16x32_bf16(af, bfr, acc[s], 0, 0, 0);
        }
        __syncthreads();
    }

    int n = lm;
    if (n < NCH) {
        float bias = br[n];
#pragma unroll
        for (int s = 0; s < 4; ++s) {
#pragma unroll
            for (int v = 0; v < 4; ++v) {
                int m = mBase + wm + s * 16 + lq * 4 + v;
                int b = m >> 8; int rem = m & 255;
                int i = rem >> 4, j = rem & 15;
                int oh = 2 * i + py, ow = 2 * j + px;
                out[((size_t)(b * NCH + n) * 32 + oh) * 32 + ow] = tanhf(acc[s][v] + bias);
            }
        }
    }
}

extern "C" void kernel_launch(void* const* d_in, const int* in_sizes, int n_in,
                              void* d_out, int out_size, void* d_ws, size_t ws_size,
                              hipStream_t stream) {
    const float* noise_re = (const float*)d_in[0];
    const float* noise_im = (const float*)d_in[1];
    const int*   labels   = (const int*)d_in[2];
    const float* emb      = (const float*)d_in[3];
    const float* w1r = (const float*)d_in[4],  *w1i = (const float*)d_in[5];
    const float* b1r = (const float*)d_in[6],  *b1i = (const float*)d_in[7];
    const float* g1rr = (const float*)d_in[8], *g1ri = (const float*)d_in[9], *g1ii = (const float*)d_in[10];
    const float* n1br = (const float*)d_in[11], *n1bi = (const float*)d_in[12];
    const float* w2r = (const float*)d_in[13], *w2i = (const float*)d_in[14];
    const float* b2r = (const float*)d_in[15], *b2i = (const float*)d_in[16];
    const float* g2rr = (const float*)d_in[17], *g2ri = (const float*)d_in[18], *g2ii = (const float*)d_in[19];
    const float* n2br = (const float*)d_in[20], *n2bi = (const float*)d_in[21];
    const float* w3r = (const float*)d_in[22], *w3i = (const float*)d_in[23];
    const float* b3r = (const float*)d_in[24], *b3i = (const float*)d_in[25];
    const float* g3rr = (const float*)d_in[26], *g3ri = (const float*)d_in[27], *g3ii = (const float*)d_in[28];
    const float* n3br = (const float*)d_in[29], *n3bi = (const float*)d_in[30];
    const float* w4r = (const float*)d_in[31], *w4i = (const float*)d_in[32];
    const float* b4r = (const float*)d_in[33], *b4i = (const float*)d_in[34];

    // ---- workspace layout (bytes) ----
    char* ws = (char*)d_ws;
    bf16* y3cl = (bf16*)ws;
    bf16* x1cl = (bf16*)ws;
    bf16* B1    = (bf16*)(ws + 8388608);
    bf16* W2all = (bf16*)(ws + 15728640);
    bf16* y2cl  = (bf16*)(ws + 33554432);
    bf16* W3all = (bf16*)(ws + 50331648);
    bf16* x0bf  = (bf16*)(ws + 54547456);
    bf16* W4all = (bf16*)(ws + 54662144);
    float* S1 = (float*)(ws + 54793216);
    float* S2 = (float*)(ws + 54875136);
    float* S3 = (float*)(ws + 54916096);
    // 1KB zero-page in the unused gap between W3all end (54525952) and x0bf (54547456)
    float* Zb = (float*)(ws + 54526976);

    prep_combined<<<NB_W1 + NB_W2 + NB_W3 + NB_W4 + NB_X0 + NB_Z, 256, 0, stream>>>(
        w1r, w1i, w2r, w2i, w3r, w3i, w4r, w4i,
        noise_re, noise_im, labels, emb,
        B1, W2all, W3all, W4all, x0bf, S1, Zb);

    // L1 GEMM (+BN1 stats, sharded) -> x1cl
    gemm1<<<dim3(2, 128), 256, 0, stream>>>(x0bf, B1, b1r, b1i, x1cl, S1);
    bn_apply_v3<<<2048, 256, 0, stream>>>(x1cl, S1, g1rr, g1ri, g1ii, n1br, n1bi,
                                          C1, 524288, 1.f / 4096.f);

    // L2 GEMM (+BN2 stats) -> y2cl
    gemm_convt_bd<C1, 4, C2><<<dim3(32, 4, 4), 256, 0, stream>>>(x1cl, W2all, b2r, b2i, y2cl, S2);
    bn_apply_v3<<<4096, 256, 0, stream>>>(y2cl, S2, g2rr, g2ri, g2ii, n2br, n2bi,
                                          C2, 1048576, 1.f / 16384.f);

    // L3 GEMM (+BN3 stats) -> y3cl : 256x256 8-wave counted-vmcnt schedule (A+B via LDS)
    gemm3_8ph<<<dim3(256), 512, 0, stream>>>(y2cl, W3all, b3r, b3i, y3cl, S3,
                                             (const bf16*)Zb);
    bn_apply_v3<<<8192, 256, 0, stream>>>(y3cl, S3, g3rr, g3ri, g3ii, n3br, n3bi,
                                          C3, 2097152, 1.f / 65536.f);

    // L4: MFMA + tanh -> d_out (real part, fp32), M-tile 256
    conv4_mfma<<<dim3(256, 1, 4), 256, 0, stream>>>(y3cl, W4all, b4r, (float*)d_out);
}